// Round 12
// baseline (626.639 us; speedup 1.0000x reference)
//
#include <hip/hip_runtime.h>
#include <math.h>

// Interaction Network — LDS-free MFMA edge kernels (ILP x2) + single-pass
// multisplit bucketed aggregation (no replicated scan).
//  K0 zero  : counts/cursors
//  K1 nodef : pack x -> f16x4
//  K2 msg   : emsg = MLP_R1([x[dst],x[src],ea]), mfma_32x32x16_f16 (r10 verbatim)
//  K3 count : per-bucket (dst>>12) edge counts
//  K4 split : multisplit scatter of {dst, m01, m23} (12B) into dense buckets
//  K5 accum : per-(bucket,slice) dense scan -> LDS f32 bins -> scratch partials
//  K6 red   : aggr[n] = sum_s partial[b][s][n]
//  K7 node  : xt = MLP_O([x, aggr]) -> packed f16x4
//  K8 out   : out = sigmoid(MLP_R2([xt[dst],xt[src],emsg])) (r10 verbatim)
// Layer-1 K layout: k0-2 xd | 3 pad | 4-6 xs | 7 pad | 8-11 ea/msg | 12 bias | 13-15 pad
// C layout (HW-verified): col=lane&31, row=(reg&3)+8*(reg>>2)+4*(lane>>5).

typedef __fp16 hf8 __attribute__((ext_vector_type(8)));
typedef _Float16 f16x2 __attribute__((ext_vector_type(2)));
typedef float f32x16 __attribute__((ext_vector_type(16)));
typedef unsigned u32x4 __attribute__((ext_vector_type(4)));

#define NEPC  64   // edges per wave-chunk (two MFMA column tiles X/Y)
#define BS    4096 // nodes per aggregation bin
#define NBMAX 32   // max buckets (N=100K -> 25)

__device__ __forceinline__ f32x16 mfma16(hf8 a, hf8 b, f32x16 c) {
    return __builtin_amdgcn_mfma_f32_32x32x16_f16(a, b, c, 0, 0, 0);
}
__device__ __forceinline__ unsigned pk2(float a, float b) {
    return __builtin_bit_cast(unsigned, __builtin_amdgcn_cvt_pkrtz(a, b));
}
__device__ __forceinline__ unsigned pk2_relu(float a, float b) {
    return __builtin_bit_cast(unsigned,
        __builtin_amdgcn_cvt_pkrtz(fmaxf(a, 0.f), fmaxf(b, 0.f)));
}
__device__ __forceinline__ unsigned pswap(unsigned v) {
    return (unsigned)__shfl_xor((int)v, 32, 64);   // partner lane = lane ^ 32
}
__device__ __forceinline__ hf8 frag_from(unsigned a, unsigned b, unsigned c, unsigned d) {
    u32x4 v = {a, b, c, d};
    return __builtin_bit_cast(hf8, v);
}

__device__ __forceinline__ void build_frags(const f32x16& t0, const f32x16& t1,
                                            int hi, hf8& F0, hf8& F1, hf8& F2) {
    const unsigned w0 = pk2_relu(t0[0],  t0[1]);
    const unsigned w1 = pk2_relu(t0[2],  t0[3]);
    const unsigned w2 = pk2_relu(t0[4],  t0[5]);
    const unsigned w3 = pk2_relu(t0[6],  t0[7]);
    const unsigned w4 = pk2_relu(t0[8],  t0[9]);
    const unsigned w5 = pk2_relu(t0[10], t0[11]);
    const unsigned w6 = pk2_relu(t0[12], t0[13]);
    const unsigned w7 = pk2_relu(t0[14], t0[15]);
    const unsigned w8 = pk2_relu(t1[0],  t1[1]);
    const unsigned w9 = pk2_relu(t1[2],  t1[3]);
    const unsigned p0 = pswap(w0), p1 = pswap(w1), p2 = pswap(w2), p3 = pswap(w3);
    const unsigned p4 = pswap(w4), p5 = pswap(w5), p6 = pswap(w6), p7 = pswap(w7);
    const unsigned p8 = pswap(w8), p9 = pswap(w9);
    F0 = frag_from(hi ? p2 : w0, hi ? p3 : w1, hi ? w2 : p0, hi ? w3 : p1);
    F1 = frag_from(hi ? p6 : w4, hi ? p7 : w5, hi ? w6 : p4, hi ? w7 : p5);
    F2 = frag_from(hi ? 0x00003c00u : w8, hi ? 0u : w9, hi ? 0u : p8, hi ? 0u : p9);
}

template<int IN, int OUT>
__device__ hf8 load_wfrag(const float* __restrict__ w, const float* __restrict__ b,
                          int mt, int ks, int lane) {
    const int r = mt * 32 + (lane & 31);
    const int kbase = ks * 16 + ((lane >> 5) & 1) * 8;
    hf8 f;
#pragma unroll
    for (int j = 0; j < 8; ++j) {
        const int k = kbase + j;
        float v = 0.f;
        if (r < OUT) {
            if (k < IN) v = w[r * IN + k];
            else if (k == IN) v = b[r];
        }
        f[j] = (__fp16)v;
    }
    return f;
}

template<int OUT>
__device__ hf8 load_wfrag_l1(const float* __restrict__ w, const float* __restrict__ b,
                             int mt, int lane) {
    const int r = mt * 32 + (lane & 31);
    const int kbase = ((lane >> 5) & 1) * 8;
    hf8 f;
#pragma unroll
    for (int j = 0; j < 8; ++j) {
        const int k = kbase + j;
        float v = 0.f;
        if (r < OUT) {
            int src = -1;
            if (k < 3) src = k;                       // xd
            else if (k >= 4 && k < 7) src = k - 1;    // xs
            else if (k >= 8 && k < 12) src = k - 2;   // ea/msg
            if (src >= 0) v = w[r * 10 + src];
            else if (k == 12) v = b[r];
        }
        f[j] = (__fp16)v;
    }
    return f;
}

template<bool IS_MSG>
__global__ __launch_bounds__(256, 2) void edge_kernel(
    const uint2* __restrict__ nodef,
    const int*   __restrict__ ei,
    const void*  __restrict__ eattr,
    const float* __restrict__ w1, const float* __restrict__ b1,
    const float* __restrict__ w2, const float* __restrict__ b2,
    const float* __restrict__ w3, const float* __restrict__ b3,
    uint2* __restrict__ emsg_out,
    float* __restrict__ out,
    int n_edges)
{
    const int lane = threadIdx.x & 63;
    const int ecol = lane & 31;
    const int hi = lane >> 5;

    hf8 wa1[2], wa2[2][3], wa3[3];
#pragma unroll
    for (int t = 0; t < 2; ++t) wa1[t] = load_wfrag_l1<40>(w1, b1, t, lane);
#pragma unroll
    for (int t = 0; t < 2; ++t)
#pragma unroll
        for (int s = 0; s < 3; ++s) wa2[t][s] = load_wfrag<40, 40>(w2, b2, t, s, lane);
#pragma unroll
    for (int s = 0; s < 3; ++s)
        wa3[s] = load_wfrag<40, (IS_MSG ? 4 : 1)>(w3, b3, 0, s, lane);

    const int gwave = (int)((blockIdx.x * blockDim.x + threadIdx.x) >> 6);
    const int nwave = (int)((gridDim.x * blockDim.x) >> 6);
    const int nchunk = (n_edges + NEPC - 1) / NEPC;
    const int last = n_edges - 1;

    int c = gwave;
    if (c >= nchunk) return;
    auto eclampX = [&](int cc) { int e = cc * NEPC + ecol;      return e < last ? e : last; };
    auto eclampY = [&](int cc) { int e = cc * NEPC + 32 + ecol; return e < last ? e : last; };

    uint2 fAX, fBX, fAY, fBY;
    int sNX = 0, dNX = 0, sNY = 0, dNY = 0;
    {
        const int eX = eclampX(c), eY = eclampY(c);
        if (hi == 0) {
            const int sX = ei[eX], dX = ei[n_edges + eX];
            const int sY = ei[eY], dY = ei[n_edges + eY];
            fAX = nodef[dX]; fBX = nodef[sX];
            fAY = nodef[dY]; fBY = nodef[sY];
            const int e2X = eclampX(c + nwave), e2Y = eclampY(c + nwave);
            sNX = ei[e2X]; dNX = ei[n_edges + e2X];
            sNY = ei[e2Y]; dNY = ei[n_edges + e2Y];
        } else {
            if (IS_MSG) {
                const float4 evX = ((const float4*)eattr)[eX];
                fAX = make_uint2(pk2(evX.x, evX.y), pk2(evX.z, evX.w));
                const float4 evY = ((const float4*)eattr)[eY];
                fAY = make_uint2(pk2(evY.x, evY.y), pk2(evY.z, evY.w));
            } else {
                fAX = ((const uint2*)eattr)[eX];
                fAY = ((const uint2*)eattr)[eY];
            }
            fBX = make_uint2(0x00003c00u, 0u);
            fBY = fBX;
        }
    }

    for (; c < nchunk; ) {
        const int cn = c + nwave;

        const hf8 bfX = frag_from(fAX.x, fAX.y, fBX.x, fBX.y);
        const hf8 bfY = frag_from(fAY.x, fAY.y, fBY.x, fBY.y);

        uint2 nfAX = fAX, nfBX = fBX, nfAY = fAY, nfBY = fBY;
        int sPX = sNX, dPX = dNX, sPY = sNY, dPY = dNY;
        {
            if (hi == 0) {
                nfAX = nodef[dNX]; nfBX = nodef[sNX];
                nfAY = nodef[dNY]; nfBY = nodef[sNY];
                const int e3X = eclampX(cn + nwave), e3Y = eclampY(cn + nwave);
                sPX = ei[e3X]; dPX = ei[n_edges + e3X];
                sPY = ei[e3Y]; dPY = ei[n_edges + e3Y];
            } else {
                const int e2X = eclampX(cn), e2Y = eclampY(cn);
                if (IS_MSG) {
                    const float4 evX = ((const float4*)eattr)[e2X];
                    nfAX = make_uint2(pk2(evX.x, evX.y), pk2(evX.z, evX.w));
                    const float4 evY = ((const float4*)eattr)[e2Y];
                    nfAY = make_uint2(pk2(evY.x, evY.y), pk2(evY.z, evY.w));
                } else {
                    nfAX = ((const uint2*)eattr)[e2X];
                    nfAY = ((const uint2*)eattr)[e2Y];
                }
            }
        }

        f32x16 a0X = {}, a1X = {}, a0Y = {}, a1Y = {};
        a0X = mfma16(wa1[0], bfX, a0X);
        a0Y = mfma16(wa1[0], bfY, a0Y);
        a1X = mfma16(wa1[1], bfX, a1X);
        a1Y = mfma16(wa1[1], bfY, a1Y);

        hf8 f0X, f1X, f2X, f0Y, f1Y, f2Y;
        build_frags(a0X, a1X, hi, f0X, f1X, f2X);
        build_frags(a0Y, a1Y, hi, f0Y, f1Y, f2Y);

        f32x16 c0X = {}, c1X = {}, c0Y = {}, c1Y = {};
        c0X = mfma16(wa2[0][0], f0X, c0X); c0Y = mfma16(wa2[0][0], f0Y, c0Y);
        c1X = mfma16(wa2[1][0], f0X, c1X); c1Y = mfma16(wa2[1][0], f0Y, c1Y);
        c0X = mfma16(wa2[0][1], f1X, c0X); c0Y = mfma16(wa2[0][1], f1Y, c0Y);
        c1X = mfma16(wa2[1][1], f1X, c1X); c1Y = mfma16(wa2[1][1], f1Y, c1Y);
        c0X = mfma16(wa2[0][2], f2X, c0X); c0Y = mfma16(wa2[0][2], f2Y, c0Y);
        c1X = mfma16(wa2[1][2], f2X, c1X); c1Y = mfma16(wa2[1][2], f2Y, c1Y);

        hf8 g0X, g1X, g2X, g0Y, g1Y, g2Y;
        build_frags(c0X, c1X, hi, g0X, g1X, g2X);
        build_frags(c0Y, c1Y, hi, g0Y, g1Y, g2Y);

        f32x16 z0X = {}, z0Y = {};
        z0X = mfma16(wa3[0], g0X, z0X); z0Y = mfma16(wa3[0], g0Y, z0Y);
        z0X = mfma16(wa3[1], g1X, z0X); z0Y = mfma16(wa3[1], g1Y, z0Y);
        z0X = mfma16(wa3[2], g2X, z0X); z0Y = mfma16(wa3[2], g2Y, z0Y);

        if (hi == 0) {
            const int eX = c * NEPC + ecol;
            const int eY = eX + 32;
            if (eX < n_edges) {
                if (IS_MSG)
                    emsg_out[eX] = make_uint2(pk2(z0X[0], z0X[1]), pk2(z0X[2], z0X[3]));
                else
                    out[eX] = 1.f / (1.f + expf(-z0X[0]));
            }
            if (eY < n_edges) {
                if (IS_MSG)
                    emsg_out[eY] = make_uint2(pk2(z0Y[0], z0Y[1]), pk2(z0Y[2], z0Y[3]));
                else
                    out[eY] = 1.f / (1.f + expf(-z0Y[0]));
            }
        }

        fAX = nfAX; fBX = nfBX; fAY = nfAY; fBY = nfBY;
        sNX = sPX; dNX = dPX; sNY = sPY; dNY = dPY;
        c = cn;
    }
}

// ---- small zero kernel: counts + cursors ----
__global__ __launch_bounds__(64) void zero_small(unsigned* __restrict__ p, int n) {
    int i = threadIdx.x;
    if (i < n) p[i] = 0u;
}

// ---- node feature packing ----
__global__ __launch_bounds__(256) void nodef_kernel(
    const float* __restrict__ x, uint2* __restrict__ nodef, int n_nodes)
{
    int n = blockIdx.x * blockDim.x + threadIdx.x;
    if (n >= n_nodes) return;
    nodef[n] = make_uint2(pk2(x[n * 3 + 0], x[n * 3 + 1]), pk2(x[n * 3 + 2], 0.f));
}

// ---- aggregation A: per-bucket counts ----
__global__ __launch_bounds__(1024) void count_kernel(
    const int* __restrict__ dstp, unsigned* __restrict__ counts, int n_edges)
{
    __shared__ unsigned lc[NBMAX];
    if (threadIdx.x < NBMAX) lc[threadIdx.x] = 0u;
    __syncthreads();
    const int stride = gridDim.x * 1024;
    for (int e = blockIdx.x * 1024 + threadIdx.x; e < n_edges; e += stride)
        atomicAdd(&lc[((unsigned)dstp[e]) >> 12], 1u);
    __syncthreads();
    if (threadIdx.x < NBMAX && lc[threadIdx.x])
        atomicAdd(&counts[threadIdx.x], lc[threadIdx.x]);
}

// ---- aggregation B: multisplit scatter of {dst, m01, m23} (12B records) ----
__global__ __launch_bounds__(1024) void split_kernel(
    const int* __restrict__ dstp,
    const uint2* __restrict__ emsg,
    const unsigned* __restrict__ counts,
    unsigned* __restrict__ cursor,
    unsigned* __restrict__ buckets,   // 3 u32 per record, bucket-contiguous
    int n_edges, int nbins)
{
    __shared__ unsigned lcnt[NBMAX], loff[NBMAX], gbase[NBMAX], gcnt[NBMAX];
    __shared__ unsigned stage[1024 * 3];   // 12KB
    const int tid = threadIdx.x;
    const int e = blockIdx.x * 1024 + tid;
    const bool valid = e < n_edges;

    if (tid < NBMAX) { lcnt[tid] = 0u; gcnt[tid] = (tid < nbins) ? counts[tid] : 0u; }
    __syncthreads();

    unsigned d = 0, b = 0, slot = 0; uint2 m = make_uint2(0u, 0u);
    if (valid) {
        d = (unsigned)dstp[e];
        m = emsg[e];
        b = d >> 12;
        slot = atomicAdd(&lcnt[b], 1u);
    }
    __syncthreads();

    if (tid == 0) {
        unsigned run = 0, gpre = 0;
        for (int i = 0; i < nbins; ++i) {
            loff[i] = run; run += lcnt[i];
            gbase[i] = gpre + atomicAdd(&cursor[i], lcnt[i]);
            gpre += gcnt[i];
        }
    }
    __syncthreads();

    if (valid) {
        const unsigned p = (loff[b] + slot) * 3;
        stage[p] = d; stage[p + 1] = m.x; stage[p + 2] = m.y;
    }
    __syncthreads();

    const int total = min(1024, n_edges - blockIdx.x * 1024);
    if (tid < total) {
        const unsigned dd = stage[tid * 3];
        const unsigned bb = dd >> 12;
        const unsigned gpos = gbase[bb] + ((unsigned)tid - loff[bb]);
        unsigned* o = buckets + (size_t)gpos * 3;
        o[0] = dd; o[1] = stage[tid * 3 + 1]; o[2] = stage[tid * 3 + 2];
    }
}

// ---- aggregation C: dense per-(bucket,slice) LDS accumulate -> scratch ----
__global__ __launch_bounds__(1024) void accum_kernel(
    const unsigned* __restrict__ buckets,
    const unsigned* __restrict__ counts,
    float* __restrict__ scratch,      // [B*S][BS*4]
    int nbins, int S)
{
    __shared__ float bin[BS * 4];     // 64 KB
    __shared__ unsigned seg[2];
    const int bid = blockIdx.x / S, s = blockIdx.x % S;
    const int tid = threadIdx.x;

#pragma unroll
    for (int i = 0; i < (BS * 4) / 1024; ++i)
        bin[tid + i * 1024] = 0.f;
    if (tid == 0) {
        unsigned start = 0;
        for (int i = 0; i < bid; ++i) start += counts[i];
        seg[0] = start; seg[1] = counts[bid];
    }
    __syncthreads();

    const unsigned start = seg[0], len = seg[1];
    const unsigned r0 = start + (unsigned)((unsigned long long)len * s / S);
    const unsigned r1 = start + (unsigned)((unsigned long long)len * (s + 1) / S);
    for (unsigned r = r0 + tid; r < r1; r += 1024) {
        const unsigned* rec = buckets + (size_t)r * 3;
        const unsigned d   = rec[0];
        const unsigned m01 = rec[1];
        const unsigned m23 = rec[2];
        const f16x2 lo = __builtin_bit_cast(f16x2, m01);
        const f16x2 hi = __builtin_bit_cast(f16x2, m23);
        float* p = bin + (d & (BS - 1)) * 4;
        atomicAdd(p + 0, (float)lo.x);
        atomicAdd(p + 1, (float)lo.y);
        atomicAdd(p + 2, (float)hi.x);
        atomicAdd(p + 3, (float)hi.y);
    }
    __syncthreads();

    float4* dst = (float4*)(scratch + ((size_t)(bid * S + s)) * BS * 4);
    const float4* srcb = (const float4*)bin;
#pragma unroll
    for (int i = 0; i < (BS * 4) / 4 / 1024; ++i)
        dst[tid + i * 1024] = srcb[tid + i * 1024];
}

// ---- aggregation D: sum slice partials -> aggr f32[N][4] ----
__global__ __launch_bounds__(256) void reduce_kernel(
    const float* __restrict__ scratch,
    float* __restrict__ aggr,
    int n_nodes, int nw)
{
    int n = blockIdx.x * blockDim.x + threadIdx.x;
    if (n >= n_nodes) return;
    const int b = n / BS, nl = n % BS;
    float4 acc = make_float4(0.f, 0.f, 0.f, 0.f);
    for (int w = 0; w < nw; ++w) {
        const float4 v = *(const float4*)(scratch + ((size_t)(b * nw + w) * BS + nl) * 4);
        acc.x += v.x; acc.y += v.y; acc.z += v.z; acc.w += v.w;
    }
    *(float4*)(aggr + (size_t)n * 4) = acc;
}

template<int IN, int OUT, bool RELU>
__device__ __forceinline__ void dense(const float* __restrict__ w,
                                      const float* __restrict__ b,
                                      const float* in, float* out) {
#pragma unroll
    for (int j = 0; j < OUT; ++j) {
        float acc = b[j];
#pragma unroll
        for (int k = 0; k < IN; ++k) acc = fmaf(w[j * IN + k], in[k], acc);
        out[j] = RELU ? fmaxf(acc, 0.f) : acc;
    }
}

__global__ __launch_bounds__(256) void node_kernel(
    const float* __restrict__ x,
    const float* __restrict__ aggr,
    const float* __restrict__ w1, const float* __restrict__ b1,
    const float* __restrict__ w2, const float* __restrict__ b2,
    const float* __restrict__ w3, const float* __restrict__ b3,
    uint2* __restrict__ xth,
    int n_nodes)
{
    int n = blockIdx.x * blockDim.x + threadIdx.x;
    if (n >= n_nodes) return;

    float in[7];
    in[0] = x[n * 3 + 0]; in[1] = x[n * 3 + 1]; in[2] = x[n * 3 + 2];
    const float4 ag = *(const float4*)(aggr + (size_t)n * 4);
    in[3] = ag.x; in[4] = ag.y; in[5] = ag.z; in[6] = ag.w;

    float h1[40], h2[40], o[3];
    dense<7, 40, true >(w1, b1, in, h1);
    dense<40, 40, true>(w2, b2, h1, h2);
    dense<40, 3, false>(w3, b3, h2, o);

    xth[n] = make_uint2(pk2(o[0], o[1]), pk2(o[2], 0.f));
}

extern "C" void kernel_launch(void* const* d_in, const int* in_sizes, int n_in,
                              void* d_out, int out_size, void* d_ws, size_t ws_size,
                              hipStream_t stream) {
    const float* x  = (const float*)d_in[0];
    const int*   ei = (const int*)d_in[1];   // int64 delivered as int32
    const float* ea = (const float*)d_in[2];

    const float* r1_w1 = (const float*)d_in[3];
    const float* r1_b1 = (const float*)d_in[4];
    const float* r1_w2 = (const float*)d_in[5];
    const float* r1_b2 = (const float*)d_in[6];
    const float* r1_w3 = (const float*)d_in[7];
    const float* r1_b3 = (const float*)d_in[8];

    const float* o_w1 = (const float*)d_in[9];
    const float* o_b1 = (const float*)d_in[10];
    const float* o_w2 = (const float*)d_in[11];
    const float* o_b2 = (const float*)d_in[12];
    const float* o_w3 = (const float*)d_in[13];
    const float* o_b3 = (const float*)d_in[14];

    const float* r2_w1 = (const float*)d_in[15];
    const float* r2_b1 = (const float*)d_in[16];
    const float* r2_w2 = (const float*)d_in[17];
    const float* r2_b2 = (const float*)d_in[18];
    const float* r2_w3 = (const float*)d_in[19];
    const float* r2_b3 = (const float*)d_in[20];

    const int n_nodes = in_sizes[0] / 3;
    const int n_edges = in_sizes[2] / 4;
    const int B = (n_nodes + BS - 1) / BS;        // 25 buckets

    // ws layout:
    //  nodef uint2[N] | aggr f32[N*4] | emsg uint2[E] | buckets u32[E*3] |
    //  counts u32[NBMAX] | cursors u32[NBMAX] | scratch f32[B*S*BS*4]
    uint2*    nodef   = (uint2*)d_ws;
    float*    aggr    = (float*)(nodef + n_nodes);
    uint2*    emsg    = (uint2*)(aggr + (size_t)n_nodes * 4);
    unsigned* buckets = (unsigned*)(emsg + n_edges);
    unsigned* counts  = buckets + (size_t)n_edges * 3;
    unsigned* cursor  = counts + NBMAX;
    float*    scratch = (float*)(cursor + NBMAX);

    const size_t fixed_bytes = (char*)scratch - (char*)d_ws;
    int S = 16;                                   // slices per bucket
    while (S > 4 && ws_size < fixed_bytes + (size_t)B * S * BS * 4 * sizeof(float))
        S >>= 1;

    const int eb = 512;                           // 2048 waves = full residency
    const int nb = (n_nodes + 255) / 256;
    const int sb = (n_edges + 1023) / 1024;       // split tiles

    zero_small<<<1, 64, 0, stream>>>(counts, 2 * NBMAX);

    nodef_kernel<<<nb, 256, 0, stream>>>(x, nodef, n_nodes);

    edge_kernel<true><<<eb, 256, 0, stream>>>(nodef, ei, (const void*)ea,
        r1_w1, r1_b1, r1_w2, r1_b2, r1_w3, r1_b3,
        emsg, nullptr, n_edges);

    count_kernel<<<512, 1024, 0, stream>>>(ei + n_edges, counts, n_edges);

    split_kernel<<<sb, 1024, 0, stream>>>(ei + n_edges, emsg, counts, cursor,
                                          buckets, n_edges, B);

    accum_kernel<<<B * S, 1024, 0, stream>>>(buckets, counts, scratch, B, S);

    reduce_kernel<<<nb, 256, 0, stream>>>(scratch, aggr, n_nodes, S);

    node_kernel<<<nb, 256, 0, stream>>>(x, aggr,
        o_w1, o_b1, o_w2, o_b2, o_w3, o_b3, nodef, n_nodes);

    edge_kernel<false><<<eb, 256, 0, stream>>>(nodef, ei, (const void*)emsg,
        r2_w1, r2_b1, r2_w2, r2_b2, r2_w3, r2_b3,
        nullptr, (float*)d_out, n_edges);
}

// Round 13
// 210.086 us; speedup vs baseline: 2.9828x; 2.9828x over previous
//
#include <hip/hip_runtime.h>
#include <math.h>

// Interaction Network — LDS-free MFMA edge kernels (ILP x2) + atomic-free
// multisplit bucketed aggregation (prefix-sum offsets, deterministic).
//  K0 nodef : pack x -> f16x4
//  K1 msg   : emsg = MLP_R1([x[dst],x[src],ea]), mfma_32x32x16_f16 (r10 verbatim)
//  K2 count : per-(tile,bucket) counts (LDS only)
//  K3 scan  : per-bucket exclusive prefix over tiles (in place) + totals
//  K4 base  : exclusive scan of 25 bucket totals
//  K5 split : scatter {dst, m01, m23} (12B) into dense buckets, offsets static
//  K6 accum : per-(bucket,slice) dense scan -> LDS f32 bins -> scratch partials
//  K7 red   : aggr[n] = sum_s partial[b][s][n]
//  K8 node  : xt = MLP_O([x, aggr]) -> packed f16x4
//  K9 out   : out = sigmoid(MLP_R2([xt[dst],xt[src],emsg])) (r10 verbatim)
// Layer-1 K layout: k0-2 xd | 3 pad | 4-6 xs | 7 pad | 8-11 ea/msg | 12 bias | 13-15 pad
// C layout (HW-verified): col=lane&31, row=(reg&3)+8*(reg>>2)+4*(lane>>5).

typedef __fp16 hf8 __attribute__((ext_vector_type(8)));
typedef _Float16 f16x2 __attribute__((ext_vector_type(2)));
typedef float f32x16 __attribute__((ext_vector_type(16)));
typedef unsigned u32x4 __attribute__((ext_vector_type(4)));

#define NEPC  64   // edges per wave-chunk (two MFMA column tiles X/Y)
#define BS    4096 // nodes per aggregation bin
#define NBMAX 32   // max buckets (N=100K -> 25)
#define TS    1024 // split tile size

__device__ __forceinline__ f32x16 mfma16(hf8 a, hf8 b, f32x16 c) {
    return __builtin_amdgcn_mfma_f32_32x32x16_f16(a, b, c, 0, 0, 0);
}
__device__ __forceinline__ unsigned pk2(float a, float b) {
    return __builtin_bit_cast(unsigned, __builtin_amdgcn_cvt_pkrtz(a, b));
}
__device__ __forceinline__ unsigned pk2_relu(float a, float b) {
    return __builtin_bit_cast(unsigned,
        __builtin_amdgcn_cvt_pkrtz(fmaxf(a, 0.f), fmaxf(b, 0.f)));
}
__device__ __forceinline__ unsigned pswap(unsigned v) {
    return (unsigned)__shfl_xor((int)v, 32, 64);   // partner lane = lane ^ 32
}
__device__ __forceinline__ hf8 frag_from(unsigned a, unsigned b, unsigned c, unsigned d) {
    u32x4 v = {a, b, c, d};
    return __builtin_bit_cast(hf8, v);
}

__device__ __forceinline__ void build_frags(const f32x16& t0, const f32x16& t1,
                                            int hi, hf8& F0, hf8& F1, hf8& F2) {
    const unsigned w0 = pk2_relu(t0[0],  t0[1]);
    const unsigned w1 = pk2_relu(t0[2],  t0[3]);
    const unsigned w2 = pk2_relu(t0[4],  t0[5]);
    const unsigned w3 = pk2_relu(t0[6],  t0[7]);
    const unsigned w4 = pk2_relu(t0[8],  t0[9]);
    const unsigned w5 = pk2_relu(t0[10], t0[11]);
    const unsigned w6 = pk2_relu(t0[12], t0[13]);
    const unsigned w7 = pk2_relu(t0[14], t0[15]);
    const unsigned w8 = pk2_relu(t1[0],  t1[1]);
    const unsigned w9 = pk2_relu(t1[2],  t1[3]);
    const unsigned p0 = pswap(w0), p1 = pswap(w1), p2 = pswap(w2), p3 = pswap(w3);
    const unsigned p4 = pswap(w4), p5 = pswap(w5), p6 = pswap(w6), p7 = pswap(w7);
    const unsigned p8 = pswap(w8), p9 = pswap(w9);
    F0 = frag_from(hi ? p2 : w0, hi ? p3 : w1, hi ? w2 : p0, hi ? w3 : p1);
    F1 = frag_from(hi ? p6 : w4, hi ? p7 : w5, hi ? w6 : p4, hi ? w7 : p5);
    F2 = frag_from(hi ? 0x00003c00u : w8, hi ? 0u : w9, hi ? 0u : p8, hi ? 0u : p9);
}

template<int IN, int OUT>
__device__ hf8 load_wfrag(const float* __restrict__ w, const float* __restrict__ b,
                          int mt, int ks, int lane) {
    const int r = mt * 32 + (lane & 31);
    const int kbase = ks * 16 + ((lane >> 5) & 1) * 8;
    hf8 f;
#pragma unroll
    for (int j = 0; j < 8; ++j) {
        const int k = kbase + j;
        float v = 0.f;
        if (r < OUT) {
            if (k < IN) v = w[r * IN + k];
            else if (k == IN) v = b[r];
        }
        f[j] = (__fp16)v;
    }
    return f;
}

template<int OUT>
__device__ hf8 load_wfrag_l1(const float* __restrict__ w, const float* __restrict__ b,
                             int mt, int lane) {
    const int r = mt * 32 + (lane & 31);
    const int kbase = ((lane >> 5) & 1) * 8;
    hf8 f;
#pragma unroll
    for (int j = 0; j < 8; ++j) {
        const int k = kbase + j;
        float v = 0.f;
        if (r < OUT) {
            int src = -1;
            if (k < 3) src = k;                       // xd
            else if (k >= 4 && k < 7) src = k - 1;    // xs
            else if (k >= 8 && k < 12) src = k - 2;   // ea/msg
            if (src >= 0) v = w[r * 10 + src];
            else if (k == 12) v = b[r];
        }
        f[j] = (__fp16)v;
    }
    return f;
}

template<bool IS_MSG>
__global__ __launch_bounds__(256, 2) void edge_kernel(
    const uint2* __restrict__ nodef,
    const int*   __restrict__ ei,
    const void*  __restrict__ eattr,
    const float* __restrict__ w1, const float* __restrict__ b1,
    const float* __restrict__ w2, const float* __restrict__ b2,
    const float* __restrict__ w3, const float* __restrict__ b3,
    uint2* __restrict__ emsg_out,
    float* __restrict__ out,
    int n_edges)
{
    const int lane = threadIdx.x & 63;
    const int ecol = lane & 31;
    const int hi = lane >> 5;

    hf8 wa1[2], wa2[2][3], wa3[3];
#pragma unroll
    for (int t = 0; t < 2; ++t) wa1[t] = load_wfrag_l1<40>(w1, b1, t, lane);
#pragma unroll
    for (int t = 0; t < 2; ++t)
#pragma unroll
        for (int s = 0; s < 3; ++s) wa2[t][s] = load_wfrag<40, 40>(w2, b2, t, s, lane);
#pragma unroll
    for (int s = 0; s < 3; ++s)
        wa3[s] = load_wfrag<40, (IS_MSG ? 4 : 1)>(w3, b3, 0, s, lane);

    const int gwave = (int)((blockIdx.x * blockDim.x + threadIdx.x) >> 6);
    const int nwave = (int)((gridDim.x * blockDim.x) >> 6);
    const int nchunk = (n_edges + NEPC - 1) / NEPC;
    const int last = n_edges - 1;

    int c = gwave;
    if (c >= nchunk) return;
    auto eclampX = [&](int cc) { int e = cc * NEPC + ecol;      return e < last ? e : last; };
    auto eclampY = [&](int cc) { int e = cc * NEPC + 32 + ecol; return e < last ? e : last; };

    uint2 fAX, fBX, fAY, fBY;
    int sNX = 0, dNX = 0, sNY = 0, dNY = 0;
    {
        const int eX = eclampX(c), eY = eclampY(c);
        if (hi == 0) {
            const int sX = ei[eX], dX = ei[n_edges + eX];
            const int sY = ei[eY], dY = ei[n_edges + eY];
            fAX = nodef[dX]; fBX = nodef[sX];
            fAY = nodef[dY]; fBY = nodef[sY];
            const int e2X = eclampX(c + nwave), e2Y = eclampY(c + nwave);
            sNX = ei[e2X]; dNX = ei[n_edges + e2X];
            sNY = ei[e2Y]; dNY = ei[n_edges + e2Y];
        } else {
            if (IS_MSG) {
                const float4 evX = ((const float4*)eattr)[eX];
                fAX = make_uint2(pk2(evX.x, evX.y), pk2(evX.z, evX.w));
                const float4 evY = ((const float4*)eattr)[eY];
                fAY = make_uint2(pk2(evY.x, evY.y), pk2(evY.z, evY.w));
            } else {
                fAX = ((const uint2*)eattr)[eX];
                fAY = ((const uint2*)eattr)[eY];
            }
            fBX = make_uint2(0x00003c00u, 0u);
            fBY = fBX;
        }
    }

    for (; c < nchunk; ) {
        const int cn = c + nwave;

        const hf8 bfX = frag_from(fAX.x, fAX.y, fBX.x, fBX.y);
        const hf8 bfY = frag_from(fAY.x, fAY.y, fBY.x, fBY.y);

        uint2 nfAX = fAX, nfBX = fBX, nfAY = fAY, nfBY = fBY;
        int sPX = sNX, dPX = dNX, sPY = sNY, dPY = dNY;
        {
            if (hi == 0) {
                nfAX = nodef[dNX]; nfBX = nodef[sNX];
                nfAY = nodef[dNY]; nfBY = nodef[sNY];
                const int e3X = eclampX(cn + nwave), e3Y = eclampY(cn + nwave);
                sPX = ei[e3X]; dPX = ei[n_edges + e3X];
                sPY = ei[e3Y]; dPY = ei[n_edges + e3Y];
            } else {
                const int e2X = eclampX(cn), e2Y = eclampY(cn);
                if (IS_MSG) {
                    const float4 evX = ((const float4*)eattr)[e2X];
                    nfAX = make_uint2(pk2(evX.x, evX.y), pk2(evX.z, evX.w));
                    const float4 evY = ((const float4*)eattr)[e2Y];
                    nfAY = make_uint2(pk2(evY.x, evY.y), pk2(evY.z, evY.w));
                } else {
                    nfAX = ((const uint2*)eattr)[e2X];
                    nfAY = ((const uint2*)eattr)[e2Y];
                }
            }
        }

        f32x16 a0X = {}, a1X = {}, a0Y = {}, a1Y = {};
        a0X = mfma16(wa1[0], bfX, a0X);
        a0Y = mfma16(wa1[0], bfY, a0Y);
        a1X = mfma16(wa1[1], bfX, a1X);
        a1Y = mfma16(wa1[1], bfY, a1Y);

        hf8 f0X, f1X, f2X, f0Y, f1Y, f2Y;
        build_frags(a0X, a1X, hi, f0X, f1X, f2X);
        build_frags(a0Y, a1Y, hi, f0Y, f1Y, f2Y);

        f32x16 c0X = {}, c1X = {}, c0Y = {}, c1Y = {};
        c0X = mfma16(wa2[0][0], f0X, c0X); c0Y = mfma16(wa2[0][0], f0Y, c0Y);
        c1X = mfma16(wa2[1][0], f0X, c1X); c1Y = mfma16(wa2[1][0], f0Y, c1Y);
        c0X = mfma16(wa2[0][1], f1X, c0X); c0Y = mfma16(wa2[0][1], f1Y, c0Y);
        c1X = mfma16(wa2[1][1], f1X, c1X); c1Y = mfma16(wa2[1][1], f1Y, c1Y);
        c0X = mfma16(wa2[0][2], f2X, c0X); c0Y = mfma16(wa2[0][2], f2Y, c0Y);
        c1X = mfma16(wa2[1][2], f2X, c1X); c1Y = mfma16(wa2[1][2], f2Y, c1Y);

        hf8 g0X, g1X, g2X, g0Y, g1Y, g2Y;
        build_frags(c0X, c1X, hi, g0X, g1X, g2X);
        build_frags(c0Y, c1Y, hi, g0Y, g1Y, g2Y);

        f32x16 z0X = {}, z0Y = {};
        z0X = mfma16(wa3[0], g0X, z0X); z0Y = mfma16(wa3[0], g0Y, z0Y);
        z0X = mfma16(wa3[1], g1X, z0X); z0Y = mfma16(wa3[1], g1Y, z0Y);
        z0X = mfma16(wa3[2], g2X, z0X); z0Y = mfma16(wa3[2], g2Y, z0Y);

        if (hi == 0) {
            const int eX = c * NEPC + ecol;
            const int eY = eX + 32;
            if (eX < n_edges) {
                if (IS_MSG)
                    emsg_out[eX] = make_uint2(pk2(z0X[0], z0X[1]), pk2(z0X[2], z0X[3]));
                else
                    out[eX] = 1.f / (1.f + expf(-z0X[0]));
            }
            if (eY < n_edges) {
                if (IS_MSG)
                    emsg_out[eY] = make_uint2(pk2(z0Y[0], z0Y[1]), pk2(z0Y[2], z0Y[3]));
                else
                    out[eY] = 1.f / (1.f + expf(-z0Y[0]));
            }
        }

        fAX = nfAX; fBX = nfBX; fAY = nfAY; fBY = nfBY;
        sNX = sPX; dNX = dPX; sNY = sPY; dNY = dPY;
        c = cn;
    }
}

// ---- node feature packing ----
__global__ __launch_bounds__(256) void nodef_kernel(
    const float* __restrict__ x, uint2* __restrict__ nodef, int n_nodes)
{
    int n = blockIdx.x * blockDim.x + threadIdx.x;
    if (n >= n_nodes) return;
    nodef[n] = make_uint2(pk2(x[n * 3 + 0], x[n * 3 + 1]), pk2(x[n * 3 + 2], 0.f));
}

// ---- A: per-(tile,bucket) counts (LDS atomics only) ----
__global__ __launch_bounds__(TS) void count_kernel(
    const int* __restrict__ dstp, unsigned* __restrict__ tilecnt, int n_edges)
{
    __shared__ unsigned lc[NBMAX];
    const int tid = threadIdx.x;
    if (tid < NBMAX) lc[tid] = 0u;
    __syncthreads();
    const int e = blockIdx.x * TS + tid;
    if (e < n_edges) atomicAdd(&lc[((unsigned)dstp[e]) >> 12], 1u);
    __syncthreads();
    if (tid < NBMAX) tilecnt[(size_t)blockIdx.x * NBMAX + tid] = lc[tid];
}

// ---- B: per-bucket exclusive prefix over tiles (in place) + totals ----
__global__ __launch_bounds__(1024) void scan_kernel(
    unsigned* __restrict__ tilecnt, unsigned* __restrict__ totals, int ntiles)
{
    __shared__ unsigned buf[1024];
    const int b = blockIdx.x;
    const int tid = threadIdx.x;
    unsigned carry = 0;
    for (int base = 0; base < ntiles; base += 1024) {
        const int i = base + tid;
        const unsigned v = (i < ntiles) ? tilecnt[(size_t)i * NBMAX + b] : 0u;
        buf[tid] = v;
        __syncthreads();
        for (int off = 1; off < 1024; off <<= 1) {
            const unsigned t = (tid >= off) ? buf[tid - off] : 0u;
            __syncthreads();
            buf[tid] += t;
            __syncthreads();
        }
        if (i < ntiles) tilecnt[(size_t)i * NBMAX + b] = (buf[tid] - v) + carry;
        carry += buf[1023];
        __syncthreads();
    }
    if (tid == 0) totals[b] = carry;
}

// ---- C: exclusive scan of bucket totals ----
__global__ __launch_bounds__(64) void base_kernel(
    const unsigned* __restrict__ totals, unsigned* __restrict__ bases, int nbins)
{
    if (threadIdx.x == 0) {
        unsigned run = 0;
        for (int i = 0; i < nbins; ++i) { bases[i] = run; run += totals[i]; }
    }
}

// ---- D: multisplit scatter, static offsets (no global atomics) ----
__global__ __launch_bounds__(TS) void split_kernel(
    const int* __restrict__ dstp,
    const uint2* __restrict__ emsg,
    const unsigned* __restrict__ tilecnt,   // exclusive per-tile offsets
    const unsigned* __restrict__ bases,
    unsigned* __restrict__ buckets,         // 3 u32 per record, bucket-contiguous
    int n_edges, int nbins)
{
    __shared__ unsigned lcnt[NBMAX], loff[NBMAX], gbase[NBMAX];
    __shared__ unsigned stage[TS * 3];      // 12KB
    const int tid = threadIdx.x;
    const int e = blockIdx.x * TS + tid;
    const bool valid = e < n_edges;

    if (tid < NBMAX) lcnt[tid] = 0u;
    __syncthreads();

    unsigned d = 0, b = 0, slot = 0; uint2 m = make_uint2(0u, 0u);
    if (valid) {
        d = (unsigned)dstp[e];
        m = emsg[e];
        b = d >> 12;
        slot = atomicAdd(&lcnt[b], 1u);
    }
    __syncthreads();

    if (tid < NBMAX && tid < (unsigned)nbins) {
        gbase[tid] = bases[tid] + tilecnt[(size_t)blockIdx.x * NBMAX + tid];
    }
    if (tid == 0) {
        unsigned run = 0;
        for (int i = 0; i < nbins; ++i) { loff[i] = run; run += lcnt[i]; }
    }
    __syncthreads();

    if (valid) {
        const unsigned p = (loff[b] + slot) * 3;
        stage[p] = d; stage[p + 1] = m.x; stage[p + 2] = m.y;
    }
    __syncthreads();

    const int total = min(TS, n_edges - blockIdx.x * TS);
    if (tid < total) {
        const unsigned dd = stage[tid * 3];
        const unsigned bb = dd >> 12;
        const unsigned gpos = gbase[bb] + ((unsigned)tid - loff[bb]);
        unsigned* o = buckets + (size_t)gpos * 3;
        o[0] = dd; o[1] = stage[tid * 3 + 1]; o[2] = stage[tid * 3 + 2];
    }
}

// ---- E: dense per-(bucket,slice) LDS accumulate -> scratch ----
typedef _Float16 hf2 __attribute__((ext_vector_type(2)));
__global__ __launch_bounds__(1024) void accum_kernel(
    const unsigned* __restrict__ buckets,
    const unsigned* __restrict__ totals,
    const unsigned* __restrict__ bases,
    float* __restrict__ scratch,      // [B*S][BS*4]
    int S)
{
    __shared__ float bin[BS * 4];     // 64 KB
    const int bid = blockIdx.x / S, s = blockIdx.x % S;
    const int tid = threadIdx.x;

#pragma unroll
    for (int i = 0; i < (BS * 4) / 1024; ++i)
        bin[tid + i * 1024] = 0.f;
    __syncthreads();

    const unsigned start = bases[bid], len = totals[bid];
    const unsigned r0 = start + (unsigned)((unsigned long long)len * s / S);
    const unsigned r1 = start + (unsigned)((unsigned long long)len * (s + 1) / S);
    for (unsigned r = r0 + tid; r < r1; r += 1024) {
        const unsigned* rec = buckets + (size_t)r * 3;
        const unsigned d   = rec[0];
        const unsigned m01 = rec[1];
        const unsigned m23 = rec[2];
        const hf2 lo = __builtin_bit_cast(hf2, m01);
        const hf2 hi = __builtin_bit_cast(hf2, m23);
        float* p = bin + (d & (BS - 1)) * 4;
        atomicAdd(p + 0, (float)lo.x);
        atomicAdd(p + 1, (float)lo.y);
        atomicAdd(p + 2, (float)hi.x);
        atomicAdd(p + 3, (float)hi.y);
    }
    __syncthreads();

    float4* dst = (float4*)(scratch + ((size_t)(bid * S + s)) * BS * 4);
    const float4* srcb = (const float4*)bin;
#pragma unroll
    for (int i = 0; i < (BS * 4) / 4 / 1024; ++i)
        dst[tid + i * 1024] = srcb[tid + i * 1024];
}

// ---- F: sum slice partials -> aggr f32[N][4] ----
__global__ __launch_bounds__(256) void reduce_kernel(
    const float* __restrict__ scratch,
    float* __restrict__ aggr,
    int n_nodes, int nw)
{
    int n = blockIdx.x * blockDim.x + threadIdx.x;
    if (n >= n_nodes) return;
    const int b = n / BS, nl = n % BS;
    float4 acc = make_float4(0.f, 0.f, 0.f, 0.f);
    for (int w = 0; w < nw; ++w) {
        const float4 v = *(const float4*)(scratch + ((size_t)(b * nw + w) * BS + nl) * 4);
        acc.x += v.x; acc.y += v.y; acc.z += v.z; acc.w += v.w;
    }
    *(float4*)(aggr + (size_t)n * 4) = acc;
}

template<int IN, int OUT, bool RELU>
__device__ __forceinline__ void dense(const float* __restrict__ w,
                                      const float* __restrict__ b,
                                      const float* in, float* out) {
#pragma unroll
    for (int j = 0; j < OUT; ++j) {
        float acc = b[j];
#pragma unroll
        for (int k = 0; k < IN; ++k) acc = fmaf(w[j * IN + k], in[k], acc);
        out[j] = RELU ? fmaxf(acc, 0.f) : acc;
    }
}

__global__ __launch_bounds__(256) void node_kernel(
    const float* __restrict__ x,
    const float* __restrict__ aggr,
    const float* __restrict__ w1, const float* __restrict__ b1,
    const float* __restrict__ w2, const float* __restrict__ b2,
    const float* __restrict__ w3, const float* __restrict__ b3,
    uint2* __restrict__ xth,
    int n_nodes)
{
    int n = blockIdx.x * blockDim.x + threadIdx.x;
    if (n >= n_nodes) return;

    float in[7];
    in[0] = x[n * 3 + 0]; in[1] = x[n * 3 + 1]; in[2] = x[n * 3 + 2];
    const float4 ag = *(const float4*)(aggr + (size_t)n * 4);
    in[3] = ag.x; in[4] = ag.y; in[5] = ag.z; in[6] = ag.w;

    float h1[40], h2[40], o[3];
    dense<7, 40, true >(w1, b1, in, h1);
    dense<40, 40, true>(w2, b2, h1, h2);
    dense<40, 3, false>(w3, b3, h2, o);

    xth[n] = make_uint2(pk2(o[0], o[1]), pk2(o[2], 0.f));
}

extern "C" void kernel_launch(void* const* d_in, const int* in_sizes, int n_in,
                              void* d_out, int out_size, void* d_ws, size_t ws_size,
                              hipStream_t stream) {
    const float* x  = (const float*)d_in[0];
    const int*   ei = (const int*)d_in[1];   // int64 delivered as int32
    const float* ea = (const float*)d_in[2];

    const float* r1_w1 = (const float*)d_in[3];
    const float* r1_b1 = (const float*)d_in[4];
    const float* r1_w2 = (const float*)d_in[5];
    const float* r1_b2 = (const float*)d_in[6];
    const float* r1_w3 = (const float*)d_in[7];
    const float* r1_b3 = (const float*)d_in[8];

    const float* o_w1 = (const float*)d_in[9];
    const float* o_b1 = (const float*)d_in[10];
    const float* o_w2 = (const float*)d_in[11];
    const float* o_b2 = (const float*)d_in[12];
    const float* o_w3 = (const float*)d_in[13];
    const float* o_b3 = (const float*)d_in[14];

    const float* r2_w1 = (const float*)d_in[15];
    const float* r2_b1 = (const float*)d_in[16];
    const float* r2_w2 = (const float*)d_in[17];
    const float* r2_b2 = (const float*)d_in[18];
    const float* r2_w3 = (const float*)d_in[19];
    const float* r2_b3 = (const float*)d_in[20];

    const int n_nodes = in_sizes[0] / 3;
    const int n_edges = in_sizes[2] / 4;
    const int B = (n_nodes + BS - 1) / BS;        // 25 buckets
    const int ntiles = (n_edges + TS - 1) / TS;   // split tiles

    // ws layout:
    //  nodef uint2[N] | aggr f32[N*4] | emsg uint2[E] | buckets u32[E*3] |
    //  totals u32[NBMAX] | bases u32[NBMAX] | tilecnt u32[ntiles*NBMAX] |
    //  scratch f32[B*S*BS*4]
    uint2*    nodef   = (uint2*)d_ws;
    float*    aggr    = (float*)(nodef + n_nodes);
    uint2*    emsg    = (uint2*)(aggr + (size_t)n_nodes * 4);
    unsigned* buckets = (unsigned*)(emsg + n_edges);
    unsigned* totals  = buckets + (size_t)n_edges * 3;
    unsigned* bases   = totals + NBMAX;
    unsigned* tilecnt = bases + NBMAX;
    float*    scratch = (float*)(tilecnt + (size_t)ntiles * NBMAX);

    const size_t fixed_bytes = (char*)scratch - (char*)d_ws;
    int S = 16;                                   // slices per bucket
    while (S > 4 && ws_size < fixed_bytes + (size_t)B * S * BS * 4 * sizeof(float))
        S >>= 1;

    const int eb = 512;                           // 2048 waves = full residency
    const int nb = (n_nodes + 255) / 256;

    nodef_kernel<<<nb, 256, 0, stream>>>(x, nodef, n_nodes);

    edge_kernel<true><<<eb, 256, 0, stream>>>(nodef, ei, (const void*)ea,
        r1_w1, r1_b1, r1_w2, r1_b2, r1_w3, r1_b3,
        emsg, nullptr, n_edges);

    count_kernel<<<ntiles, TS, 0, stream>>>(ei + n_edges, tilecnt, n_edges);

    scan_kernel<<<B, 1024, 0, stream>>>(tilecnt, totals, ntiles);

    base_kernel<<<1, 64, 0, stream>>>(totals, bases, B);

    split_kernel<<<ntiles, TS, 0, stream>>>(ei + n_edges, emsg, tilecnt, bases,
                                            buckets, n_edges, B);

    accum_kernel<<<B * S, 1024, 0, stream>>>(buckets, totals, bases, scratch, S);

    reduce_kernel<<<nb, 256, 0, stream>>>(scratch, aggr, n_nodes, S);

    node_kernel<<<nb, 256, 0, stream>>>(x, aggr,
        o_w1, o_b1, o_w2, o_b2, o_w3, o_b3, nodef, n_nodes);

    edge_kernel<false><<<eb, 256, 0, stream>>>(nodef, ei, (const void*)emsg,
        r2_w1, r2_b1, r2_w2, r2_b2, r2_w3, r2_b3,
        nullptr, (float*)d_out, n_edges);
}

// Round 14
// 183.680 us; speedup vs baseline: 3.4116x; 1.1438x over previous
//
#include <hip/hip_runtime.h>
#include <math.h>

// Interaction Network — LDS-free MFMA edge kernels (ILP x2) + atomic-free
// multisplit aggregation with packed-f16 LDS bins (ds_pk_add_f16).
//  K0 nodef : pack x -> f16x4
//  K1 msg   : emsg = MLP_R1([x[dst],x[src],ea]), mfma_32x32x16_f16 (r10 verbatim)
//  K2 count : per-(tile,bucket) counts (LDS only)
//  K3 scan  : per-bucket exclusive prefix over tiles (in place) + totals
//  K4 base  : exclusive scan of 25 bucket totals
//  K5 split : scatter dst->bd[], msg->bm[] into dense buckets (static offsets)
//  K6 accum : per-(bucket,slice) dense scan -> f16x4 LDS bins (pk_add) -> scratch
//  K7 red   : aggr[n] = f32 sum of S f16x4 partials
//  K8 node  : xt = MLP_O([x, aggr]) -> packed f16x4
//  K9 out   : out = sigmoid(MLP_R2([xt[dst],xt[src],emsg])) (r10 verbatim)
// Layer-1 K layout: k0-2 xd | 3 pad | 4-6 xs | 7 pad | 8-11 ea/msg | 12 bias | 13-15 pad
// C layout (HW-verified): col=lane&31, row=(reg&3)+8*(reg>>2)+4*(lane>>5).

typedef __fp16 hf8 __attribute__((ext_vector_type(8)));
typedef _Float16 f16x2 __attribute__((ext_vector_type(2)));
typedef float f32x16 __attribute__((ext_vector_type(16)));
typedef unsigned u32x4 __attribute__((ext_vector_type(4)));

#define NEPC  64   // edges per wave-chunk (two MFMA column tiles X/Y)
#define BS    4096 // nodes per aggregation bin
#define NBMAX 32   // max buckets (N=100K -> 25)
#define TS    1024 // split tile size

__device__ __forceinline__ f32x16 mfma16(hf8 a, hf8 b, f32x16 c) {
    return __builtin_amdgcn_mfma_f32_32x32x16_f16(a, b, c, 0, 0, 0);
}
__device__ __forceinline__ unsigned pk2(float a, float b) {
    return __builtin_bit_cast(unsigned, __builtin_amdgcn_cvt_pkrtz(a, b));
}
__device__ __forceinline__ unsigned pk2_relu(float a, float b) {
    return __builtin_bit_cast(unsigned,
        __builtin_amdgcn_cvt_pkrtz(fmaxf(a, 0.f), fmaxf(b, 0.f)));
}
__device__ __forceinline__ unsigned pswap(unsigned v) {
    return (unsigned)__shfl_xor((int)v, 32, 64);   // partner lane = lane ^ 32
}
__device__ __forceinline__ hf8 frag_from(unsigned a, unsigned b, unsigned c, unsigned d) {
    u32x4 v = {a, b, c, d};
    return __builtin_bit_cast(hf8, v);
}

__device__ __forceinline__ void build_frags(const f32x16& t0, const f32x16& t1,
                                            int hi, hf8& F0, hf8& F1, hf8& F2) {
    const unsigned w0 = pk2_relu(t0[0],  t0[1]);
    const unsigned w1 = pk2_relu(t0[2],  t0[3]);
    const unsigned w2 = pk2_relu(t0[4],  t0[5]);
    const unsigned w3 = pk2_relu(t0[6],  t0[7]);
    const unsigned w4 = pk2_relu(t0[8],  t0[9]);
    const unsigned w5 = pk2_relu(t0[10], t0[11]);
    const unsigned w6 = pk2_relu(t0[12], t0[13]);
    const unsigned w7 = pk2_relu(t0[14], t0[15]);
    const unsigned w8 = pk2_relu(t1[0],  t1[1]);
    const unsigned w9 = pk2_relu(t1[2],  t1[3]);
    const unsigned p0 = pswap(w0), p1 = pswap(w1), p2 = pswap(w2), p3 = pswap(w3);
    const unsigned p4 = pswap(w4), p5 = pswap(w5), p6 = pswap(w6), p7 = pswap(w7);
    const unsigned p8 = pswap(w8), p9 = pswap(w9);
    F0 = frag_from(hi ? p2 : w0, hi ? p3 : w1, hi ? w2 : p0, hi ? w3 : p1);
    F1 = frag_from(hi ? p6 : w4, hi ? p7 : w5, hi ? w6 : p4, hi ? w7 : p5);
    F2 = frag_from(hi ? 0x00003c00u : w8, hi ? 0u : w9, hi ? 0u : p8, hi ? 0u : p9);
}

template<int IN, int OUT>
__device__ hf8 load_wfrag(const float* __restrict__ w, const float* __restrict__ b,
                          int mt, int ks, int lane) {
    const int r = mt * 32 + (lane & 31);
    const int kbase = ks * 16 + ((lane >> 5) & 1) * 8;
    hf8 f;
#pragma unroll
    for (int j = 0; j < 8; ++j) {
        const int k = kbase + j;
        float v = 0.f;
        if (r < OUT) {
            if (k < IN) v = w[r * IN + k];
            else if (k == IN) v = b[r];
        }
        f[j] = (__fp16)v;
    }
    return f;
}

template<int OUT>
__device__ hf8 load_wfrag_l1(const float* __restrict__ w, const float* __restrict__ b,
                             int mt, int lane) {
    const int r = mt * 32 + (lane & 31);
    const int kbase = ((lane >> 5) & 1) * 8;
    hf8 f;
#pragma unroll
    for (int j = 0; j < 8; ++j) {
        const int k = kbase + j;
        float v = 0.f;
        if (r < OUT) {
            int src = -1;
            if (k < 3) src = k;                       // xd
            else if (k >= 4 && k < 7) src = k - 1;    // xs
            else if (k >= 8 && k < 12) src = k - 2;   // ea/msg
            if (src >= 0) v = w[r * 10 + src];
            else if (k == 12) v = b[r];
        }
        f[j] = (__fp16)v;
    }
    return f;
}

template<bool IS_MSG>
__global__ __launch_bounds__(256, 2) void edge_kernel(
    const uint2* __restrict__ nodef,
    const int*   __restrict__ ei,
    const void*  __restrict__ eattr,
    const float* __restrict__ w1, const float* __restrict__ b1,
    const float* __restrict__ w2, const float* __restrict__ b2,
    const float* __restrict__ w3, const float* __restrict__ b3,
    uint2* __restrict__ emsg_out,
    float* __restrict__ out,
    int n_edges)
{
    const int lane = threadIdx.x & 63;
    const int ecol = lane & 31;
    const int hi = lane >> 5;

    hf8 wa1[2], wa2[2][3], wa3[3];
#pragma unroll
    for (int t = 0; t < 2; ++t) wa1[t] = load_wfrag_l1<40>(w1, b1, t, lane);
#pragma unroll
    for (int t = 0; t < 2; ++t)
#pragma unroll
        for (int s = 0; s < 3; ++s) wa2[t][s] = load_wfrag<40, 40>(w2, b2, t, s, lane);
#pragma unroll
    for (int s = 0; s < 3; ++s)
        wa3[s] = load_wfrag<40, (IS_MSG ? 4 : 1)>(w3, b3, 0, s, lane);

    const int gwave = (int)((blockIdx.x * blockDim.x + threadIdx.x) >> 6);
    const int nwave = (int)((gridDim.x * blockDim.x) >> 6);
    const int nchunk = (n_edges + NEPC - 1) / NEPC;
    const int last = n_edges - 1;

    int c = gwave;
    if (c >= nchunk) return;
    auto eclampX = [&](int cc) { int e = cc * NEPC + ecol;      return e < last ? e : last; };
    auto eclampY = [&](int cc) { int e = cc * NEPC + 32 + ecol; return e < last ? e : last; };

    uint2 fAX, fBX, fAY, fBY;
    int sNX = 0, dNX = 0, sNY = 0, dNY = 0;
    {
        const int eX = eclampX(c), eY = eclampY(c);
        if (hi == 0) {
            const int sX = ei[eX], dX = ei[n_edges + eX];
            const int sY = ei[eY], dY = ei[n_edges + eY];
            fAX = nodef[dX]; fBX = nodef[sX];
            fAY = nodef[dY]; fBY = nodef[sY];
            const int e2X = eclampX(c + nwave), e2Y = eclampY(c + nwave);
            sNX = ei[e2X]; dNX = ei[n_edges + e2X];
            sNY = ei[e2Y]; dNY = ei[n_edges + e2Y];
        } else {
            if (IS_MSG) {
                const float4 evX = ((const float4*)eattr)[eX];
                fAX = make_uint2(pk2(evX.x, evX.y), pk2(evX.z, evX.w));
                const float4 evY = ((const float4*)eattr)[eY];
                fAY = make_uint2(pk2(evY.x, evY.y), pk2(evY.z, evY.w));
            } else {
                fAX = ((const uint2*)eattr)[eX];
                fAY = ((const uint2*)eattr)[eY];
            }
            fBX = make_uint2(0x00003c00u, 0u);
            fBY = fBX;
        }
    }

    for (; c < nchunk; ) {
        const int cn = c + nwave;

        const hf8 bfX = frag_from(fAX.x, fAX.y, fBX.x, fBX.y);
        const hf8 bfY = frag_from(fAY.x, fAY.y, fBY.x, fBY.y);

        uint2 nfAX = fAX, nfBX = fBX, nfAY = fAY, nfBY = fBY;
        int sPX = sNX, dPX = dNX, sPY = sNY, dPY = dNY;
        {
            if (hi == 0) {
                nfAX = nodef[dNX]; nfBX = nodef[sNX];
                nfAY = nodef[dNY]; nfBY = nodef[sNY];
                const int e3X = eclampX(cn + nwave), e3Y = eclampY(cn + nwave);
                sPX = ei[e3X]; dPX = ei[n_edges + e3X];
                sPY = ei[e3Y]; dPY = ei[n_edges + e3Y];
            } else {
                const int e2X = eclampX(cn), e2Y = eclampY(cn);
                if (IS_MSG) {
                    const float4 evX = ((const float4*)eattr)[e2X];
                    nfAX = make_uint2(pk2(evX.x, evX.y), pk2(evX.z, evX.w));
                    const float4 evY = ((const float4*)eattr)[e2Y];
                    nfAY = make_uint2(pk2(evY.x, evY.y), pk2(evY.z, evY.w));
                } else {
                    nfAX = ((const uint2*)eattr)[e2X];
                    nfAY = ((const uint2*)eattr)[e2Y];
                }
            }
        }

        f32x16 a0X = {}, a1X = {}, a0Y = {}, a1Y = {};
        a0X = mfma16(wa1[0], bfX, a0X);
        a0Y = mfma16(wa1[0], bfY, a0Y);
        a1X = mfma16(wa1[1], bfX, a1X);
        a1Y = mfma16(wa1[1], bfY, a1Y);

        hf8 f0X, f1X, f2X, f0Y, f1Y, f2Y;
        build_frags(a0X, a1X, hi, f0X, f1X, f2X);
        build_frags(a0Y, a1Y, hi, f0Y, f1Y, f2Y);

        f32x16 c0X = {}, c1X = {}, c0Y = {}, c1Y = {};
        c0X = mfma16(wa2[0][0], f0X, c0X); c0Y = mfma16(wa2[0][0], f0Y, c0Y);
        c1X = mfma16(wa2[1][0], f0X, c1X); c1Y = mfma16(wa2[1][0], f0Y, c1Y);
        c0X = mfma16(wa2[0][1], f1X, c0X); c0Y = mfma16(wa2[0][1], f1Y, c0Y);
        c1X = mfma16(wa2[1][1], f1X, c1X); c1Y = mfma16(wa2[1][1], f1Y, c1Y);
        c0X = mfma16(wa2[0][2], f2X, c0X); c0Y = mfma16(wa2[0][2], f2Y, c0Y);
        c1X = mfma16(wa2[1][2], f2X, c1X); c1Y = mfma16(wa2[1][2], f2Y, c1Y);

        hf8 g0X, g1X, g2X, g0Y, g1Y, g2Y;
        build_frags(c0X, c1X, hi, g0X, g1X, g2X);
        build_frags(c0Y, c1Y, hi, g0Y, g1Y, g2Y);

        f32x16 z0X = {}, z0Y = {};
        z0X = mfma16(wa3[0], g0X, z0X); z0Y = mfma16(wa3[0], g0Y, z0Y);
        z0X = mfma16(wa3[1], g1X, z0X); z0Y = mfma16(wa3[1], g1Y, z0Y);
        z0X = mfma16(wa3[2], g2X, z0X); z0Y = mfma16(wa3[2], g2Y, z0Y);

        if (hi == 0) {
            const int eX = c * NEPC + ecol;
            const int eY = eX + 32;
            if (eX < n_edges) {
                if (IS_MSG)
                    emsg_out[eX] = make_uint2(pk2(z0X[0], z0X[1]), pk2(z0X[2], z0X[3]));
                else
                    out[eX] = 1.f / (1.f + expf(-z0X[0]));
            }
            if (eY < n_edges) {
                if (IS_MSG)
                    emsg_out[eY] = make_uint2(pk2(z0Y[0], z0Y[1]), pk2(z0Y[2], z0Y[3]));
                else
                    out[eY] = 1.f / (1.f + expf(-z0Y[0]));
            }
        }

        fAX = nfAX; fBX = nfBX; fAY = nfAY; fBY = nfBY;
        sNX = sPX; dNX = dPX; sNY = sPY; dNY = dPY;
        c = cn;
    }
}

// ---- node feature packing ----
__global__ __launch_bounds__(256) void nodef_kernel(
    const float* __restrict__ x, uint2* __restrict__ nodef, int n_nodes)
{
    int n = blockIdx.x * blockDim.x + threadIdx.x;
    if (n >= n_nodes) return;
    nodef[n] = make_uint2(pk2(x[n * 3 + 0], x[n * 3 + 1]), pk2(x[n * 3 + 2], 0.f));
}

// ---- A: per-(tile,bucket) counts (LDS atomics only) ----
__global__ __launch_bounds__(TS) void count_kernel(
    const int* __restrict__ dstp, unsigned* __restrict__ tilecnt, int n_edges)
{
    __shared__ unsigned lc[NBMAX];
    const int tid = threadIdx.x;
    if (tid < NBMAX) lc[tid] = 0u;
    __syncthreads();
    const int e = blockIdx.x * TS + tid;
    if (e < n_edges) atomicAdd(&lc[((unsigned)dstp[e]) >> 12], 1u);
    __syncthreads();
    if (tid < NBMAX) tilecnt[(size_t)blockIdx.x * NBMAX + tid] = lc[tid];
}

// ---- B: per-bucket exclusive prefix over tiles (in place) + totals ----
__global__ __launch_bounds__(1024) void scan_kernel(
    unsigned* __restrict__ tilecnt, unsigned* __restrict__ totals, int ntiles)
{
    __shared__ unsigned buf[1024];
    const int b = blockIdx.x;
    const int tid = threadIdx.x;
    unsigned carry = 0;
    for (int base = 0; base < ntiles; base += 1024) {
        const int i = base + tid;
        const unsigned v = (i < ntiles) ? tilecnt[(size_t)i * NBMAX + b] : 0u;
        buf[tid] = v;
        __syncthreads();
        for (int off = 1; off < 1024; off <<= 1) {
            const unsigned t = (tid >= off) ? buf[tid - off] : 0u;
            __syncthreads();
            buf[tid] += t;
            __syncthreads();
        }
        if (i < ntiles) tilecnt[(size_t)i * NBMAX + b] = (buf[tid] - v) + carry;
        carry += buf[1023];
        __syncthreads();
    }
    if (tid == 0) totals[b] = carry;
}

// ---- C: exclusive scan of bucket totals ----
__global__ __launch_bounds__(64) void base_kernel(
    const unsigned* __restrict__ totals, unsigned* __restrict__ bases, int nbins)
{
    if (threadIdx.x == 0) {
        unsigned run = 0;
        for (int i = 0; i < nbins; ++i) { bases[i] = run; run += totals[i]; }
    }
}

// ---- D: multisplit scatter (SoA output), static offsets ----
__global__ __launch_bounds__(TS) void split_kernel(
    const int* __restrict__ dstp,
    const uint2* __restrict__ emsg,
    const unsigned* __restrict__ tilecnt,   // exclusive per-tile offsets
    const unsigned* __restrict__ bases,
    unsigned* __restrict__ bd,              // dst per record, bucket-contiguous
    uint2* __restrict__ bm,                 // msg per record
    int n_edges, int nbins)
{
    __shared__ unsigned lcnt[NBMAX], loff[NBMAX], gbase[NBMAX];
    __shared__ unsigned stage[TS * 3];      // 12KB
    const int tid = threadIdx.x;
    const int e = blockIdx.x * TS + tid;
    const bool valid = e < n_edges;

    if (tid < NBMAX) lcnt[tid] = 0u;
    __syncthreads();

    unsigned d = 0, b = 0, slot = 0; uint2 m = make_uint2(0u, 0u);
    if (valid) {
        d = (unsigned)dstp[e];
        m = emsg[e];
        b = d >> 12;
        slot = atomicAdd(&lcnt[b], 1u);
    }
    __syncthreads();

    if (tid < NBMAX && tid < (unsigned)nbins) {
        gbase[tid] = bases[tid] + tilecnt[(size_t)blockIdx.x * NBMAX + tid];
    }
    if (tid == 0) {
        unsigned run = 0;
        for (int i = 0; i < nbins; ++i) { loff[i] = run; run += lcnt[i]; }
    }
    __syncthreads();

    if (valid) {
        const unsigned p = (loff[b] + slot) * 3;
        stage[p] = d; stage[p + 1] = m.x; stage[p + 2] = m.y;
    }
    __syncthreads();

    const int total = min(TS, n_edges - blockIdx.x * TS);
    if (tid < total) {
        const unsigned dd = stage[tid * 3];
        const unsigned bb = dd >> 12;
        const unsigned gpos = gbase[bb] + ((unsigned)tid - loff[bb]);
        bd[gpos] = dd;
        bm[gpos] = make_uint2(stage[tid * 3 + 1], stage[tid * 3 + 2]);
    }
}

// ---- E: dense per-(bucket,slice) scan -> f16x4 LDS bins via ds_pk_add_f16 ----
typedef _Float16 hf2 __attribute__((ext_vector_type(2)));
__global__ __launch_bounds__(1024) void accum_kernel(
    const unsigned* __restrict__ bd,
    const uint2* __restrict__ bm,
    const unsigned* __restrict__ totals,
    const unsigned* __restrict__ bases,
    uint2* __restrict__ scratch,      // [B*S][BS] f16x4 partials
    int S)
{
    __shared__ unsigned bin[BS * 2];  // 32 KB, f16x4 per node
    const int bid = blockIdx.x / S, s = blockIdx.x % S;
    const int tid = threadIdx.x;

#pragma unroll
    for (int i = 0; i < (BS * 2) / 1024; ++i)
        bin[tid + i * 1024] = 0u;
    __syncthreads();

    const unsigned start = bases[bid], len = totals[bid];
    const unsigned r0 = start + (unsigned)((unsigned long long)len * s / S);
    const unsigned r1 = start + (unsigned)((unsigned long long)len * (s + 1) / S);
    for (unsigned r = r0 + tid; r < r1; r += 1024) {
        const unsigned d = bd[r];
        const uint2 m = bm[r];
        const unsigned laddr =
            (unsigned)(reinterpret_cast<uintptr_t>(&bin[(d & (BS - 1)) * 2]));
        asm volatile("ds_pk_add_f16 %0, %1" :: "v"(laddr), "v"(m.x) : "memory");
        asm volatile("ds_pk_add_f16 %0, %1 offset:4" :: "v"(laddr), "v"(m.y) : "memory");
    }
    __syncthreads();

    uint2* dst = scratch + (size_t)(bid * S + s) * BS;
    const uint2* srcb = (const uint2*)bin;
#pragma unroll
    for (int i = 0; i < BS / 1024; ++i)
        dst[tid + i * 1024] = srcb[tid + i * 1024];
}

// ---- F: f32 sum of S f16x4 partials -> aggr f32[N][4] ----
__global__ __launch_bounds__(256) void reduce_kernel(
    const uint2* __restrict__ scratch,
    float* __restrict__ aggr,
    int n_nodes, int S)
{
    int n = blockIdx.x * blockDim.x + threadIdx.x;
    if (n >= n_nodes) return;
    const int b = n / BS, nl = n % BS;
    float4 acc = make_float4(0.f, 0.f, 0.f, 0.f);
    for (int w = 0; w < S; ++w) {
        const uint2 v = scratch[(size_t)(b * S + w) * BS + nl];
        const hf2 lo = __builtin_bit_cast(hf2, v.x);
        const hf2 hi = __builtin_bit_cast(hf2, v.y);
        acc.x += (float)lo.x; acc.y += (float)lo.y;
        acc.z += (float)hi.x; acc.w += (float)hi.y;
    }
    *(float4*)(aggr + (size_t)n * 4) = acc;
}

template<int IN, int OUT, bool RELU>
__device__ __forceinline__ void dense(const float* __restrict__ w,
                                      const float* __restrict__ b,
                                      const float* in, float* out) {
#pragma unroll
    for (int j = 0; j < OUT; ++j) {
        float acc = b[j];
#pragma unroll
        for (int k = 0; k < IN; ++k) acc = fmaf(w[j * IN + k], in[k], acc);
        out[j] = RELU ? fmaxf(acc, 0.f) : acc;
    }
}

__global__ __launch_bounds__(256) void node_kernel(
    const float* __restrict__ x,
    const float* __restrict__ aggr,
    const float* __restrict__ w1, const float* __restrict__ b1,
    const float* __restrict__ w2, const float* __restrict__ b2,
    const float* __restrict__ w3, const float* __restrict__ b3,
    uint2* __restrict__ xth,
    int n_nodes)
{
    int n = blockIdx.x * blockDim.x + threadIdx.x;
    if (n >= n_nodes) return;

    float in[7];
    in[0] = x[n * 3 + 0]; in[1] = x[n * 3 + 1]; in[2] = x[n * 3 + 2];
    const float4 ag = *(const float4*)(aggr + (size_t)n * 4);
    in[3] = ag.x; in[4] = ag.y; in[5] = ag.z; in[6] = ag.w;

    float h1[40], h2[40], o[3];
    dense<7, 40, true >(w1, b1, in, h1);
    dense<40, 40, true>(w2, b2, h1, h2);
    dense<40, 3, false>(w3, b3, h2, o);

    xth[n] = make_uint2(pk2(o[0], o[1]), pk2(o[2], 0.f));
}

extern "C" void kernel_launch(void* const* d_in, const int* in_sizes, int n_in,
                              void* d_out, int out_size, void* d_ws, size_t ws_size,
                              hipStream_t stream) {
    const float* x  = (const float*)d_in[0];
    const int*   ei = (const int*)d_in[1];   // int64 delivered as int32
    const float* ea = (const float*)d_in[2];

    const float* r1_w1 = (const float*)d_in[3];
    const float* r1_b1 = (const float*)d_in[4];
    const float* r1_w2 = (const float*)d_in[5];
    const float* r1_b2 = (const float*)d_in[6];
    const float* r1_w3 = (const float*)d_in[7];
    const float* r1_b3 = (const float*)d_in[8];

    const float* o_w1 = (const float*)d_in[9];
    const float* o_b1 = (const float*)d_in[10];
    const float* o_w2 = (const float*)d_in[11];
    const float* o_b2 = (const float*)d_in[12];
    const float* o_w3 = (const float*)d_in[13];
    const float* o_b3 = (const float*)d_in[14];

    const float* r2_w1 = (const float*)d_in[15];
    const float* r2_b1 = (const float*)d_in[16];
    const float* r2_w2 = (const float*)d_in[17];
    const float* r2_b2 = (const float*)d_in[18];
    const float* r2_w3 = (const float*)d_in[19];
    const float* r2_b3 = (const float*)d_in[20];

    const int n_nodes = in_sizes[0] / 3;
    const int n_edges = in_sizes[2] / 4;
    const int B = (n_nodes + BS - 1) / BS;        // 25 buckets
    const int ntiles = (n_edges + TS - 1) / TS;   // split tiles

    // ws layout:
    //  nodef uint2[N] | aggr f32[N*4] | emsg uint2[E] | bd u32[E] | bm uint2[E] |
    //  totals u32[NBMAX] | bases u32[NBMAX] | tilecnt u32[ntiles*NBMAX] |
    //  scratch uint2[B*S*BS]
    uint2*    nodef   = (uint2*)d_ws;
    float*    aggr    = (float*)(nodef + n_nodes);
    uint2*    emsg    = (uint2*)(aggr + (size_t)n_nodes * 4);
    unsigned* bd      = (unsigned*)(emsg + n_edges);
    uint2*    bm      = (uint2*)(bd + n_edges);
    unsigned* totals  = (unsigned*)(bm + n_edges);
    unsigned* bases   = totals + NBMAX;
    unsigned* tilecnt = bases + NBMAX;
    uint2*    scratch = (uint2*)(tilecnt + (size_t)ntiles * NBMAX);

    const size_t fixed_bytes = (char*)scratch - (char*)d_ws;
    int S = 16;                                   // slices per bucket
    while (S > 4 && ws_size < fixed_bytes + (size_t)B * S * BS * sizeof(uint2))
        S >>= 1;

    const int eb = 512;                           // 2048 waves = full residency
    const int nb = (n_nodes + 255) / 256;

    nodef_kernel<<<nb, 256, 0, stream>>>(x, nodef, n_nodes);

    edge_kernel<true><<<eb, 256, 0, stream>>>(nodef, ei, (const void*)ea,
        r1_w1, r1_b1, r1_w2, r1_b2, r1_w3, r1_b3,
        emsg, nullptr, n_edges);

    count_kernel<<<ntiles, TS, 0, stream>>>(ei + n_edges, tilecnt, n_edges);

    scan_kernel<<<B, 1024, 0, stream>>>(tilecnt, totals, ntiles);

    base_kernel<<<1, 64, 0, stream>>>(totals, bases, B);

    split_kernel<<<ntiles, TS, 0, stream>>>(ei + n_edges, emsg, tilecnt, bases,
                                            bd, bm, n_edges, B);

    accum_kernel<<<B * S, 1024, 0, stream>>>(bd, bm, totals, bases, scratch, S);

    reduce_kernel<<<nb, 256, 0, stream>>>(scratch, aggr, n_nodes, S);

    node_kernel<<<nb, 256, 0, stream>>>(x, aggr,
        o_w1, o_b1, o_w2, o_b2, o_w3, o_b3, nodef, n_nodes);

    edge_kernel<false><<<eb, 256, 0, stream>>>(nodef, ei, (const void*)emsg,
        r2_w1, r2_b1, r2_w2, r2_b2, r2_w3, r2_b3,
        nullptr, (float*)d_out, n_edges);
}

// Round 15
// 181.919 us; speedup vs baseline: 3.4446x; 1.0097x over previous
//
#include <hip/hip_runtime.h>
#include <math.h>

// Interaction Network — LDS-free MFMA edge kernels (ILP x2, precomputed weight
// fragment table) + atomic-free multisplit aggregation with ds_pk_add_f16 bins.
//  K-1 wprep: precompute per-lane MFMA A-fragments for R1 and R2 -> ws tables
//  K0 nodef : pack x -> f16x4
//  K1 msg   : emsg = MLP_R1([x[dst],x[src],ea]), mfma_32x32x16_f16
//  K2 count : per-(tile,bucket) counts (LDS only)
//  K3 scan  : per-bucket exclusive prefix over tiles (in place) + totals
//  K4 base  : exclusive scan of 25 bucket totals
//  K5 split : scatter dst->bd[], msg->bm[] into dense buckets (static offsets)
//  K6 accum : per-(bucket,slice) dense scan -> f16x4 LDS bins (pk_add) -> scratch
//  K7 red   : aggr[n] = f32 sum of S f16x4 partials
//  K8 node  : xt = MLP_O([x, aggr]) -> packed f16x4
//  K9 out   : out = sigmoid(MLP_R2([xt[dst],xt[src],emsg]))
// Layer-1 K layout: k0-2 xd | 3 pad | 4-6 xs | 7 pad | 8-11 ea/msg | 12 bias | 13-15 pad
// C layout (HW-verified): col=lane&31, row=(reg&3)+8*(reg>>2)+4*(lane>>5).

typedef __fp16 hf8 __attribute__((ext_vector_type(8)));
typedef _Float16 f16x2 __attribute__((ext_vector_type(2)));
typedef float f32x16 __attribute__((ext_vector_type(16)));
typedef unsigned u32x4 __attribute__((ext_vector_type(4)));

#define NEPC  64   // edges per wave-chunk (two MFMA column tiles X/Y)
#define BS    4096 // nodes per aggregation bin
#define NBMAX 32   // max buckets (N=100K -> 25)
#define TS    1024 // split tile size
#define NFRAG 11   // weight fragments per edge MLP

__device__ __forceinline__ f32x16 mfma16(hf8 a, hf8 b, f32x16 c) {
    return __builtin_amdgcn_mfma_f32_32x32x16_f16(a, b, c, 0, 0, 0);
}
__device__ __forceinline__ unsigned pk2(float a, float b) {
    return __builtin_bit_cast(unsigned, __builtin_amdgcn_cvt_pkrtz(a, b));
}
__device__ __forceinline__ unsigned pk2_relu(float a, float b) {
    return __builtin_bit_cast(unsigned,
        __builtin_amdgcn_cvt_pkrtz(fmaxf(a, 0.f), fmaxf(b, 0.f)));
}
__device__ __forceinline__ unsigned pswap(unsigned v) {
    return (unsigned)__shfl_xor((int)v, 32, 64);   // partner lane = lane ^ 32
}
__device__ __forceinline__ hf8 frag_from(unsigned a, unsigned b, unsigned c, unsigned d) {
    u32x4 v = {a, b, c, d};
    return __builtin_bit_cast(hf8, v);
}

__device__ __forceinline__ void build_frags(const f32x16& t0, const f32x16& t1,
                                            int hi, hf8& F0, hf8& F1, hf8& F2) {
    const unsigned w0 = pk2_relu(t0[0],  t0[1]);
    const unsigned w1 = pk2_relu(t0[2],  t0[3]);
    const unsigned w2 = pk2_relu(t0[4],  t0[5]);
    const unsigned w3 = pk2_relu(t0[6],  t0[7]);
    const unsigned w4 = pk2_relu(t0[8],  t0[9]);
    const unsigned w5 = pk2_relu(t0[10], t0[11]);
    const unsigned w6 = pk2_relu(t0[12], t0[13]);
    const unsigned w7 = pk2_relu(t0[14], t0[15]);
    const unsigned w8 = pk2_relu(t1[0],  t1[1]);
    const unsigned w9 = pk2_relu(t1[2],  t1[3]);
    const unsigned p0 = pswap(w0), p1 = pswap(w1), p2 = pswap(w2), p3 = pswap(w3);
    const unsigned p4 = pswap(w4), p5 = pswap(w5), p6 = pswap(w6), p7 = pswap(w7);
    const unsigned p8 = pswap(w8), p9 = pswap(w9);
    F0 = frag_from(hi ? p2 : w0, hi ? p3 : w1, hi ? w2 : p0, hi ? w3 : p1);
    F1 = frag_from(hi ? p6 : w4, hi ? p7 : w5, hi ? w6 : p4, hi ? w7 : p5);
    F2 = frag_from(hi ? 0x00003c00u : w8, hi ? 0u : w9, hi ? 0u : p8, hi ? 0u : p9);
}

// hidden-layer A fragment (IN=40 + bias at k=40)
template<int IN, int OUT>
__device__ hf8 load_wfrag(const float* __restrict__ w, const float* __restrict__ b,
                          int mt, int ks, int lane) {
    const int r = mt * 32 + (lane & 31);
    const int kbase = ks * 16 + ((lane >> 5) & 1) * 8;
    hf8 f;
#pragma unroll
    for (int j = 0; j < 8; ++j) {
        const int k = kbase + j;
        float v = 0.f;
        if (r < OUT) {
            if (k < IN) v = w[r * IN + k];
            else if (k == IN) v = b[r];
        }
        f[j] = (__fp16)v;
    }
    return f;
}

// layer-1 A fragment, padded K map (IN fixed at 10)
template<int OUT>
__device__ hf8 load_wfrag_l1(const float* __restrict__ w, const float* __restrict__ b,
                             int mt, int lane) {
    const int r = mt * 32 + (lane & 31);
    const int kbase = ((lane >> 5) & 1) * 8;
    hf8 f;
#pragma unroll
    for (int j = 0; j < 8; ++j) {
        const int k = kbase + j;
        float v = 0.f;
        if (r < OUT) {
            int src = -1;
            if (k < 3) src = k;                       // xd
            else if (k >= 4 && k < 7) src = k - 1;    // xs
            else if (k >= 8 && k < 12) src = k - 2;   // ea/msg
            if (src >= 0) v = w[r * 10 + src];
            else if (k == 12) v = b[r];
        }
        f[j] = (__fp16)v;
    }
    return f;
}

// ---- weight fragment table prep: tab[f*64+lane], f: wa1[0..1], wa2[0][0..2],
// wa2[1][0..2], wa3[0..2] ----
template<int OUT3>
__global__ __launch_bounds__(64) void wprep_kernel(
    const float* __restrict__ w1, const float* __restrict__ b1,
    const float* __restrict__ w2, const float* __restrict__ b2,
    const float* __restrict__ w3, const float* __restrict__ b3,
    uint4* __restrict__ tab)
{
    const int lane = threadIdx.x;
#pragma unroll
    for (int t = 0; t < 2; ++t)
        tab[t * 64 + lane] = __builtin_bit_cast(uint4, load_wfrag_l1<40>(w1, b1, t, lane));
#pragma unroll
    for (int t = 0; t < 2; ++t)
#pragma unroll
        for (int s = 0; s < 3; ++s)
            tab[(2 + t * 3 + s) * 64 + lane] =
                __builtin_bit_cast(uint4, load_wfrag<40, 40>(w2, b2, t, s, lane));
#pragma unroll
    for (int s = 0; s < 3; ++s)
        tab[(8 + s) * 64 + lane] =
            __builtin_bit_cast(uint4, load_wfrag<40, OUT3>(w3, b3, 0, s, lane));
}

template<bool IS_MSG>
__global__ __launch_bounds__(256, 2) void edge_kernel(
    const uint2* __restrict__ nodef,
    const int*   __restrict__ ei,
    const void*  __restrict__ eattr,
    const uint4* __restrict__ wtab,   // precomputed fragments
    uint2* __restrict__ emsg_out,
    float* __restrict__ out,
    int n_edges)
{
    const int lane = threadIdx.x & 63;
    const int ecol = lane & 31;
    const int hi = lane >> 5;

    // prologue: 11 coalesced 16B fragment loads
    hf8 wa1[2], wa2[2][3], wa3[3];
    wa1[0] = __builtin_bit_cast(hf8, wtab[0 * 64 + lane]);
    wa1[1] = __builtin_bit_cast(hf8, wtab[1 * 64 + lane]);
#pragma unroll
    for (int t = 0; t < 2; ++t)
#pragma unroll
        for (int s = 0; s < 3; ++s)
            wa2[t][s] = __builtin_bit_cast(hf8, wtab[(2 + t * 3 + s) * 64 + lane]);
#pragma unroll
    for (int s = 0; s < 3; ++s)
        wa3[s] = __builtin_bit_cast(hf8, wtab[(8 + s) * 64 + lane]);

    const int gwave = (int)((blockIdx.x * blockDim.x + threadIdx.x) >> 6);
    const int nwave = (int)((gridDim.x * blockDim.x) >> 6);
    const int nchunk = (n_edges + NEPC - 1) / NEPC;
    const int last = n_edges - 1;

    int c = gwave;
    if (c >= nchunk) return;
    auto eclampX = [&](int cc) { int e = cc * NEPC + ecol;      return e < last ? e : last; };
    auto eclampY = [&](int cc) { int e = cc * NEPC + 32 + ecol; return e < last ? e : last; };

    uint2 fAX, fBX, fAY, fBY;
    int sNX = 0, dNX = 0, sNY = 0, dNY = 0;
    {
        const int eX = eclampX(c), eY = eclampY(c);
        if (hi == 0) {
            const int sX = ei[eX], dX = ei[n_edges + eX];
            const int sY = ei[eY], dY = ei[n_edges + eY];
            fAX = nodef[dX]; fBX = nodef[sX];
            fAY = nodef[dY]; fBY = nodef[sY];
            const int e2X = eclampX(c + nwave), e2Y = eclampY(c + nwave);
            sNX = ei[e2X]; dNX = ei[n_edges + e2X];
            sNY = ei[e2Y]; dNY = ei[n_edges + e2Y];
        } else {
            if (IS_MSG) {
                const float4 evX = ((const float4*)eattr)[eX];
                fAX = make_uint2(pk2(evX.x, evX.y), pk2(evX.z, evX.w));
                const float4 evY = ((const float4*)eattr)[eY];
                fAY = make_uint2(pk2(evY.x, evY.y), pk2(evY.z, evY.w));
            } else {
                fAX = ((const uint2*)eattr)[eX];
                fAY = ((const uint2*)eattr)[eY];
            }
            fBX = make_uint2(0x00003c00u, 0u);   // bias word {1.0h, 0h}
            fBY = fBX;
        }
    }

    for (; c < nchunk; ) {
        const int cn = c + nwave;

        const hf8 bfX = frag_from(fAX.x, fAX.y, fBX.x, fBX.y);
        const hf8 bfY = frag_from(fAY.x, fAY.y, fBY.x, fBY.y);

        uint2 nfAX = fAX, nfBX = fBX, nfAY = fAY, nfBY = fBY;
        int sPX = sNX, dPX = dNX, sPY = sNY, dPY = dNY;
        {
            if (hi == 0) {
                nfAX = nodef[dNX]; nfBX = nodef[sNX];
                nfAY = nodef[dNY]; nfBY = nodef[sNY];
                const int e3X = eclampX(cn + nwave), e3Y = eclampY(cn + nwave);
                sPX = ei[e3X]; dPX = ei[n_edges + e3X];
                sPY = ei[e3Y]; dPY = ei[n_edges + e3Y];
            } else {
                const int e2X = eclampX(cn), e2Y = eclampY(cn);
                if (IS_MSG) {
                    const float4 evX = ((const float4*)eattr)[e2X];
                    nfAX = make_uint2(pk2(evX.x, evX.y), pk2(evX.z, evX.w));
                    const float4 evY = ((const float4*)eattr)[e2Y];
                    nfAY = make_uint2(pk2(evY.x, evY.y), pk2(evY.z, evY.w));
                } else {
                    nfAX = ((const uint2*)eattr)[e2X];
                    nfAY = ((const uint2*)eattr)[e2Y];
                }
            }
        }

        f32x16 a0X = {}, a1X = {}, a0Y = {}, a1Y = {};
        a0X = mfma16(wa1[0], bfX, a0X);
        a0Y = mfma16(wa1[0], bfY, a0Y);
        a1X = mfma16(wa1[1], bfX, a1X);
        a1Y = mfma16(wa1[1], bfY, a1Y);

        hf8 f0X, f1X, f2X, f0Y, f1Y, f2Y;
        build_frags(a0X, a1X, hi, f0X, f1X, f2X);
        build_frags(a0Y, a1Y, hi, f0Y, f1Y, f2Y);

        f32x16 c0X = {}, c1X = {}, c0Y = {}, c1Y = {};
        c0X = mfma16(wa2[0][0], f0X, c0X); c0Y = mfma16(wa2[0][0], f0Y, c0Y);
        c1X = mfma16(wa2[1][0], f0X, c1X); c1Y = mfma16(wa2[1][0], f0Y, c1Y);
        c0X = mfma16(wa2[0][1], f1X, c0X); c0Y = mfma16(wa2[0][1], f1Y, c0Y);
        c1X = mfma16(wa2[1][1], f1X, c1X); c1Y = mfma16(wa2[1][1], f1Y, c1Y);
        c0X = mfma16(wa2[0][2], f2X, c0X); c0Y = mfma16(wa2[0][2], f2Y, c0Y);
        c1X = mfma16(wa2[1][2], f2X, c1X); c1Y = mfma16(wa2[1][2], f2Y, c1Y);

        hf8 g0X, g1X, g2X, g0Y, g1Y, g2Y;
        build_frags(c0X, c1X, hi, g0X, g1X, g2X);
        build_frags(c0Y, c1Y, hi, g0Y, g1Y, g2Y);

        f32x16 z0X = {}, z0Y = {};
        z0X = mfma16(wa3[0], g0X, z0X); z0Y = mfma16(wa3[0], g0Y, z0Y);
        z0X = mfma16(wa3[1], g1X, z0X); z0Y = mfma16(wa3[1], g1Y, z0Y);
        z0X = mfma16(wa3[2], g2X, z0X); z0Y = mfma16(wa3[2], g2Y, z0Y);

        if (hi == 0) {
            const int eX = c * NEPC + ecol;
            const int eY = eX + 32;
            if (eX < n_edges) {
                if (IS_MSG)
                    emsg_out[eX] = make_uint2(pk2(z0X[0], z0X[1]), pk2(z0X[2], z0X[3]));
                else
                    out[eX] = 1.f / (1.f + expf(-z0X[0]));
            }
            if (eY < n_edges) {
                if (IS_MSG)
                    emsg_out[eY] = make_uint2(pk2(z0Y[0], z0Y[1]), pk2(z0Y[2], z0Y[3]));
                else
                    out[eY] = 1.f / (1.f + expf(-z0Y[0]));
            }
        }

        fAX = nfAX; fBX = nfBX; fAY = nfAY; fBY = nfBY;
        sNX = sPX; dNX = dPX; sNY = sPY; dNY = dPY;
        c = cn;
    }
}

// ---- node feature packing ----
__global__ __launch_bounds__(256) void nodef_kernel(
    const float* __restrict__ x, uint2* __restrict__ nodef, int n_nodes)
{
    int n = blockIdx.x * blockDim.x + threadIdx.x;
    if (n >= n_nodes) return;
    nodef[n] = make_uint2(pk2(x[n * 3 + 0], x[n * 3 + 1]), pk2(x[n * 3 + 2], 0.f));
}

// ---- A: per-(tile,bucket) counts (LDS atomics only) ----
__global__ __launch_bounds__(TS) void count_kernel(
    const int* __restrict__ dstp, unsigned* __restrict__ tilecnt, int n_edges)
{
    __shared__ unsigned lc[NBMAX];
    const int tid = threadIdx.x;
    if (tid < NBMAX) lc[tid] = 0u;
    __syncthreads();
    const int e = blockIdx.x * TS + tid;
    if (e < n_edges) atomicAdd(&lc[((unsigned)dstp[e]) >> 12], 1u);
    __syncthreads();
    if (tid < NBMAX) tilecnt[(size_t)blockIdx.x * NBMAX + tid] = lc[tid];
}

// ---- B: per-bucket exclusive prefix over tiles (in place) + totals ----
__global__ __launch_bounds__(1024) void scan_kernel(
    unsigned* __restrict__ tilecnt, unsigned* __restrict__ totals, int ntiles)
{
    __shared__ unsigned buf[1024];
    const int b = blockIdx.x;
    const int tid = threadIdx.x;
    unsigned carry = 0;
    for (int base = 0; base < ntiles; base += 1024) {
        const int i = base + tid;
        const unsigned v = (i < ntiles) ? tilecnt[(size_t)i * NBMAX + b] : 0u;
        buf[tid] = v;
        __syncthreads();
        for (int off = 1; off < 1024; off <<= 1) {
            const unsigned t = (tid >= off) ? buf[tid - off] : 0u;
            __syncthreads();
            buf[tid] += t;
            __syncthreads();
        }
        if (i < ntiles) tilecnt[(size_t)i * NBMAX + b] = (buf[tid] - v) + carry;
        carry += buf[1023];
        __syncthreads();
    }
    if (tid == 0) totals[b] = carry;
}

// ---- C: exclusive scan of bucket totals ----
__global__ __launch_bounds__(64) void base_kernel(
    const unsigned* __restrict__ totals, unsigned* __restrict__ bases, int nbins)
{
    if (threadIdx.x == 0) {
        unsigned run = 0;
        for (int i = 0; i < nbins; ++i) { bases[i] = run; run += totals[i]; }
    }
}

// ---- D: multisplit scatter (SoA output), static offsets ----
__global__ __launch_bounds__(TS) void split_kernel(
    const int* __restrict__ dstp,
    const uint2* __restrict__ emsg,
    const unsigned* __restrict__ tilecnt,   // exclusive per-tile offsets
    const unsigned* __restrict__ bases,
    unsigned* __restrict__ bd,              // dst per record, bucket-contiguous
    uint2* __restrict__ bm,                 // msg per record
    int n_edges, int nbins)
{
    __shared__ unsigned lcnt[NBMAX], loff[NBMAX], gbase[NBMAX];
    __shared__ unsigned stage[TS * 3];      // 12KB
    const int tid = threadIdx.x;
    const int e = blockIdx.x * TS + tid;
    const bool valid = e < n_edges;

    if (tid < NBMAX) lcnt[tid] = 0u;
    __syncthreads();

    unsigned d = 0, b = 0, slot = 0; uint2 m = make_uint2(0u, 0u);
    if (valid) {
        d = (unsigned)dstp[e];
        m = emsg[e];
        b = d >> 12;
        slot = atomicAdd(&lcnt[b], 1u);
    }
    __syncthreads();

    if (tid < NBMAX && tid < (unsigned)nbins) {
        gbase[tid] = bases[tid] + tilecnt[(size_t)blockIdx.x * NBMAX + tid];
    }
    if (tid == 0) {
        unsigned run = 0;
        for (int i = 0; i < nbins; ++i) { loff[i] = run; run += lcnt[i]; }
    }
    __syncthreads();

    if (valid) {
        const unsigned p = (loff[b] + slot) * 3;
        stage[p] = d; stage[p + 1] = m.x; stage[p + 2] = m.y;
    }
    __syncthreads();

    const int total = min(TS, n_edges - blockIdx.x * TS);
    if (tid < total) {
        const unsigned dd = stage[tid * 3];
        const unsigned bb = dd >> 12;
        const unsigned gpos = gbase[bb] + ((unsigned)tid - loff[bb]);
        bd[gpos] = dd;
        bm[gpos] = make_uint2(stage[tid * 3 + 1], stage[tid * 3 + 2]);
    }
}

// ---- E: dense per-(bucket,slice) scan -> f16x4 LDS bins via ds_pk_add_f16 ----
typedef _Float16 hf2 __attribute__((ext_vector_type(2)));
__global__ __launch_bounds__(1024) void accum_kernel(
    const unsigned* __restrict__ bd,
    const uint2* __restrict__ bm,
    const unsigned* __restrict__ totals,
    const unsigned* __restrict__ bases,
    uint2* __restrict__ scratch,      // [B*S][BS] f16x4 partials
    int S)
{
    __shared__ unsigned bin[BS * 2];  // 32 KB, f16x4 per node
    const int bid = blockIdx.x / S, s = blockIdx.x % S;
    const int tid = threadIdx.x;

#pragma unroll
    for (int i = 0; i < (BS * 2) / 1024; ++i)
        bin[tid + i * 1024] = 0u;
    __syncthreads();

    const unsigned start = bases[bid], len = totals[bid];
    const unsigned r0 = start + (unsigned)((unsigned long long)len * s / S);
    const unsigned r1 = start + (unsigned)((unsigned long long)len * (s + 1) / S);
    for (unsigned r = r0 + tid; r < r1; r += 1024) {
        const unsigned d = bd[r];
        const uint2 m = bm[r];
        const unsigned laddr =
            (unsigned)(reinterpret_cast<uintptr_t>(&bin[(d & (BS - 1)) * 2]));
        asm volatile("ds_pk_add_f16 %0, %1" :: "v"(laddr), "v"(m.x) : "memory");
        asm volatile("ds_pk_add_f16 %0, %1 offset:4" :: "v"(laddr), "v"(m.y) : "memory");
    }
    __syncthreads();

    uint2* dst = scratch + (size_t)(bid * S + s) * BS;
    const uint2* srcb = (const uint2*)bin;
#pragma unroll
    for (int i = 0; i < BS / 1024; ++i)
        dst[tid + i * 1024] = srcb[tid + i * 1024];
}

// ---- F: f32 sum of S f16x4 partials -> aggr f32[N][4] ----
__global__ __launch_bounds__(256) void reduce_kernel(
    const uint2* __restrict__ scratch,
    float* __restrict__ aggr,
    int n_nodes, int S)
{
    int n = blockIdx.x * blockDim.x + threadIdx.x;
    if (n >= n_nodes) return;
    const int b = n / BS, nl = n % BS;
    float4 acc = make_float4(0.f, 0.f, 0.f, 0.f);
    for (int w = 0; w < S; ++w) {
        const uint2 v = scratch[(size_t)(b * S + w) * BS + nl];
        const hf2 lo = __builtin_bit_cast(hf2, v.x);
        const hf2 hi = __builtin_bit_cast(hf2, v.y);
        acc.x += (float)lo.x; acc.y += (float)lo.y;
        acc.z += (float)hi.x; acc.w += (float)hi.y;
    }
    *(float4*)(aggr + (size_t)n * 4) = acc;
}

template<int IN, int OUT, bool RELU>
__device__ __forceinline__ void dense(const float* __restrict__ w,
                                      const float* __restrict__ b,
                                      const float* in, float* out) {
#pragma unroll
    for (int j = 0; j < OUT; ++j) {
        float acc = b[j];
#pragma unroll
        for (int k = 0; k < IN; ++k) acc = fmaf(w[j * IN + k], in[k], acc);
        out[j] = RELU ? fmaxf(acc, 0.f) : acc;
    }
}

__global__ __launch_bounds__(256) void node_kernel(
    const float* __restrict__ x,
    const float* __restrict__ aggr,
    const float* __restrict__ w1, const float* __restrict__ b1,
    const float* __restrict__ w2, const float* __restrict__ b2,
    const float* __restrict__ w3, const float* __restrict__ b3,
    uint2* __restrict__ xth,
    int n_nodes)
{
    int n = blockIdx.x * blockDim.x + threadIdx.x;
    if (n >= n_nodes) return;

    float in[7];
    in[0] = x[n * 3 + 0]; in[1] = x[n * 3 + 1]; in[2] = x[n * 3 + 2];
    const float4 ag = *(const float4*)(aggr + (size_t)n * 4);
    in[3] = ag.x; in[4] = ag.y; in[5] = ag.z; in[6] = ag.w;

    float h1[40], h2[40], o[3];
    dense<7, 40, true >(w1, b1, in, h1);
    dense<40, 40, true>(w2, b2, h1, h2);
    dense<40, 3, false>(w3, b3, h2, o);

    xth[n] = make_uint2(pk2(o[0], o[1]), pk2(o[2], 0.f));
}

extern "C" void kernel_launch(void* const* d_in, const int* in_sizes, int n_in,
                              void* d_out, int out_size, void* d_ws, size_t ws_size,
                              hipStream_t stream) {
    const float* x  = (const float*)d_in[0];
    const int*   ei = (const int*)d_in[1];   // int64 delivered as int32
    const float* ea = (const float*)d_in[2];

    const float* r1_w1 = (const float*)d_in[3];
    const float* r1_b1 = (const float*)d_in[4];
    const float* r1_w2 = (const float*)d_in[5];
    const float* r1_b2 = (const float*)d_in[6];
    const float* r1_w3 = (const float*)d_in[7];
    const float* r1_b3 = (const float*)d_in[8];

    const float* o_w1 = (const float*)d_in[9];
    const float* o_b1 = (const float*)d_in[10];
    const float* o_w2 = (const float*)d_in[11];
    const float* o_b2 = (const float*)d_in[12];
    const float* o_w3 = (const float*)d_in[13];
    const float* o_b3 = (const float*)d_in[14];

    const float* r2_w1 = (const float*)d_in[15];
    const float* r2_b1 = (const float*)d_in[16];
    const float* r2_w2 = (const float*)d_in[17];
    const float* r2_b2 = (const float*)d_in[18];
    const float* r2_w3 = (const float*)d_in[19];
    const float* r2_b3 = (const float*)d_in[20];

    const int n_nodes = in_sizes[0] / 3;
    const int n_edges = in_sizes[2] / 4;
    const int B = (n_nodes + BS - 1) / BS;        // 25 buckets
    const int ntiles = (n_edges + TS - 1) / TS;   // split tiles

    // ws layout:
    //  nodef uint2[N] | aggr f32[N*4] | emsg uint2[E] | bd u32[E] | bm uint2[E] |
    //  totals u32[NBMAX] | bases u32[NBMAX] | tilecnt u32[ntiles*NBMAX] |
    //  wtab1 uint4[NFRAG*64] | wtab2 uint4[NFRAG*64] | scratch uint2[B*S*BS]
    uint2*    nodef   = (uint2*)d_ws;
    float*    aggr    = (float*)(nodef + n_nodes);
    uint2*    emsg    = (uint2*)(aggr + (size_t)n_nodes * 4);
    unsigned* bd      = (unsigned*)(emsg + n_edges);
    uint2*    bm      = (uint2*)(bd + n_edges);
    unsigned* totals  = (unsigned*)(bm + n_edges);
    unsigned* bases   = totals + NBMAX;
    unsigned* tilecnt = bases + NBMAX;
    uint4*    wtab1   = (uint4*)(tilecnt + (size_t)ntiles * NBMAX);
    uint4*    wtab2   = wtab1 + NFRAG * 64;
    uint2*    scratch = (uint2*)(wtab2 + NFRAG * 64);

    const size_t fixed_bytes = (char*)scratch - (char*)d_ws;
    int S = 16;                                   // slices per bucket
    while (S > 4 && ws_size < fixed_bytes + (size_t)B * S * BS * sizeof(uint2))
        S >>= 1;

    const int eb = 1024;                          // 4 blocks/CU offered
    const int nb = (n_nodes + 255) / 256;

    wprep_kernel<4><<<1, 64, 0, stream>>>(r1_w1, r1_b1, r1_w2, r1_b2,
                                          r1_w3, r1_b3, wtab1);
    wprep_kernel<1><<<1, 64, 0, stream>>>(r2_w1, r2_b1, r2_w2, r2_b2,
                                          r2_w3, r2_b3, wtab2);

    nodef_kernel<<<nb, 256, 0, stream>>>(x, nodef, n_nodes);

    edge_kernel<true><<<eb, 256, 0, stream>>>(nodef, ei, (const void*)ea,
        wtab1, emsg, nullptr, n_edges);

    count_kernel<<<ntiles, TS, 0, stream>>>(ei + n_edges, tilecnt, n_edges);

    scan_kernel<<<B, 1024, 0, stream>>>(tilecnt, totals, ntiles);

    base_kernel<<<1, 64, 0, stream>>>(totals, bases, B);

    split_kernel<<<ntiles, TS, 0, stream>>>(ei + n_edges, emsg, tilecnt, bases,
                                            bd, bm, n_edges, B);

    accum_kernel<<<B * S, 1024, 0, stream>>>(bd, bm, totals, bases, scratch, S);

    reduce_kernel<<<nb, 256, 0, stream>>>(scratch, aggr, n_nodes, S);

    node_kernel<<<nb, 256, 0, stream>>>(x, aggr,
        o_w1, o_b1, o_w2, o_b2, o_w3, o_b3, nodef, n_nodes);

    edge_kernel<false><<<eb, 256, 0, stream>>>(nodef, ei, (const void*)emsg,
        wtab2, nullptr, (float*)d_out, n_edges);
}

// Round 16
// 176.500 us; speedup vs baseline: 3.5504x; 1.0307x over previous
//
#include <hip/hip_runtime.h>
#include <math.h>

// Interaction Network — LDS-free MFMA edge kernels (ILP x2, wtab prologue,
// launch_bounds(256,3)) + atomic-free multisplit aggregation, ds_pk_add_f16 bins
// with x4-unrolled accum.
// Layer-1 K layout: k0-2 xd | 3 pad | 4-6 xs | 7 pad | 8-11 ea/msg | 12 bias | 13-15 pad
// C layout (HW-verified): col=lane&31, row=(reg&3)+8*(reg>>2)+4*(lane>>5).

typedef __fp16 hf8 __attribute__((ext_vector_type(8)));
typedef _Float16 f16x2 __attribute__((ext_vector_type(2)));
typedef float f32x16 __attribute__((ext_vector_type(16)));
typedef unsigned u32x4 __attribute__((ext_vector_type(4)));

#define NEPC  64   // edges per wave-chunk (two MFMA column tiles X/Y)
#define BS    4096 // nodes per aggregation bin
#define NBMAX 32   // max buckets (N=100K -> 25)
#define TS    1024 // split tile size
#define NFRAG 11   // weight fragments per edge MLP

__device__ __forceinline__ f32x16 mfma16(hf8 a, hf8 b, f32x16 c) {
    return __builtin_amdgcn_mfma_f32_32x32x16_f16(a, b, c, 0, 0, 0);
}
__device__ __forceinline__ unsigned pk2(float a, float b) {
    return __builtin_bit_cast(unsigned, __builtin_amdgcn_cvt_pkrtz(a, b));
}
__device__ __forceinline__ unsigned pk2_relu(float a, float b) {
    return __builtin_bit_cast(unsigned,
        __builtin_amdgcn_cvt_pkrtz(fmaxf(a, 0.f), fmaxf(b, 0.f)));
}
__device__ __forceinline__ unsigned pswap(unsigned v) {
    return (unsigned)__shfl_xor((int)v, 32, 64);   // partner lane = lane ^ 32
}
__device__ __forceinline__ hf8 frag_from(unsigned a, unsigned b, unsigned c, unsigned d) {
    u32x4 v = {a, b, c, d};
    return __builtin_bit_cast(hf8, v);
}

__device__ __forceinline__ void build_frags(const f32x16& t0, const f32x16& t1,
                                            int hi, hf8& F0, hf8& F1, hf8& F2) {
    const unsigned w0 = pk2_relu(t0[0],  t0[1]);
    const unsigned w1 = pk2_relu(t0[2],  t0[3]);
    const unsigned w2 = pk2_relu(t0[4],  t0[5]);
    const unsigned w3 = pk2_relu(t0[6],  t0[7]);
    const unsigned w4 = pk2_relu(t0[8],  t0[9]);
    const unsigned w5 = pk2_relu(t0[10], t0[11]);
    const unsigned w6 = pk2_relu(t0[12], t0[13]);
    const unsigned w7 = pk2_relu(t0[14], t0[15]);
    const unsigned w8 = pk2_relu(t1[0],  t1[1]);
    const unsigned w9 = pk2_relu(t1[2],  t1[3]);
    const unsigned p0 = pswap(w0), p1 = pswap(w1), p2 = pswap(w2), p3 = pswap(w3);
    const unsigned p4 = pswap(w4), p5 = pswap(w5), p6 = pswap(w6), p7 = pswap(w7);
    const unsigned p8 = pswap(w8), p9 = pswap(w9);
    F0 = frag_from(hi ? p2 : w0, hi ? p3 : w1, hi ? w2 : p0, hi ? w3 : p1);
    F1 = frag_from(hi ? p6 : w4, hi ? p7 : w5, hi ? w6 : p4, hi ? w7 : p5);
    F2 = frag_from(hi ? 0x00003c00u : w8, hi ? 0u : w9, hi ? 0u : p8, hi ? 0u : p9);
}

// hidden-layer A fragment (IN=40 + bias at k=40), runtime OUT
__device__ hf8 load_wfrag40(const float* __restrict__ w, const float* __restrict__ b,
                            int OUT, int mt, int ks, int lane) {
    const int r = mt * 32 + (lane & 31);
    const int kbase = ks * 16 + ((lane >> 5) & 1) * 8;
    hf8 f;
#pragma unroll
    for (int j = 0; j < 8; ++j) {
        const int k = kbase + j;
        float v = 0.f;
        if (r < OUT) {
            if (k < 40) v = w[r * 40 + k];
            else if (k == 40) v = b[r];
        }
        f[j] = (__fp16)v;
    }
    return f;
}

// layer-1 A fragment, padded K map (IN fixed at 10)
__device__ hf8 load_wfrag_l1(const float* __restrict__ w, const float* __restrict__ b,
                             int mt, int lane) {
    const int r = mt * 32 + (lane & 31);
    const int kbase = ((lane >> 5) & 1) * 8;
    hf8 f;
#pragma unroll
    for (int j = 0; j < 8; ++j) {
        const int k = kbase + j;
        float v = 0.f;
        if (r < 40) {
            int src = -1;
            if (k < 3) src = k;                       // xd
            else if (k >= 4 && k < 7) src = k - 1;    // xs
            else if (k >= 8 && k < 12) src = k - 2;   // ea/msg
            if (src >= 0) v = w[r * 10 + src];
            else if (k == 12) v = b[r];
        }
        f[j] = (__fp16)v;
    }
    return f;
}

// ---- weight fragment table prep (both MLPs in one launch; block 0=R1, 1=R2) ----
__global__ __launch_bounds__(64) void wprep_kernel(
    const float* __restrict__ a_w1, const float* __restrict__ a_b1,
    const float* __restrict__ a_w2, const float* __restrict__ a_b2,
    const float* __restrict__ a_w3, const float* __restrict__ a_b3,
    const float* __restrict__ b_w1, const float* __restrict__ b_b1,
    const float* __restrict__ b_w2, const float* __restrict__ b_b2,
    const float* __restrict__ b_w3, const float* __restrict__ b_b3,
    uint4* __restrict__ tab1, uint4* __restrict__ tab2)
{
    const int lane = threadIdx.x;
    const bool second = blockIdx.x == 1;
    const float* w1 = second ? b_w1 : a_w1; const float* b1 = second ? b_b1 : a_b1;
    const float* w2 = second ? b_w2 : a_w2; const float* b2 = second ? b_b2 : a_b2;
    const float* w3 = second ? b_w3 : a_w3; const float* b3 = second ? b_b3 : a_b3;
    uint4* tab = second ? tab2 : tab1;
    const int out3 = second ? 1 : 4;
#pragma unroll
    for (int t = 0; t < 2; ++t)
        tab[t * 64 + lane] = __builtin_bit_cast(uint4, load_wfrag_l1(w1, b1, t, lane));
#pragma unroll
    for (int t = 0; t < 2; ++t)
#pragma unroll
        for (int s = 0; s < 3; ++s)
            tab[(2 + t * 3 + s) * 64 + lane] =
                __builtin_bit_cast(uint4, load_wfrag40(w2, b2, 40, t, s, lane));
#pragma unroll
    for (int s = 0; s < 3; ++s)
        tab[(8 + s) * 64 + lane] =
            __builtin_bit_cast(uint4, load_wfrag40(w3, b3, out3, 0, s, lane));
}

template<bool IS_MSG>
__global__ __launch_bounds__(256, 3) void edge_kernel(
    const uint2* __restrict__ nodef,
    const int*   __restrict__ ei,
    const void*  __restrict__ eattr,
    const uint4* __restrict__ wtab,   // precomputed fragments
    uint2* __restrict__ emsg_out,
    float* __restrict__ out,
    int n_edges)
{
    const int lane = threadIdx.x & 63;
    const int ecol = lane & 31;
    const int hi = lane >> 5;

    // prologue: 11 coalesced 16B fragment loads
    hf8 wa1[2], wa2[2][3], wa3[3];
    wa1[0] = __builtin_bit_cast(hf8, wtab[0 * 64 + lane]);
    wa1[1] = __builtin_bit_cast(hf8, wtab[1 * 64 + lane]);
#pragma unroll
    for (int t = 0; t < 2; ++t)
#pragma unroll
        for (int s = 0; s < 3; ++s)
            wa2[t][s] = __builtin_bit_cast(hf8, wtab[(2 + t * 3 + s) * 64 + lane]);
#pragma unroll
    for (int s = 0; s < 3; ++s)
        wa3[s] = __builtin_bit_cast(hf8, wtab[(8 + s) * 64 + lane]);

    const int gwave = (int)((blockIdx.x * blockDim.x + threadIdx.x) >> 6);
    const int nwave = (int)((gridDim.x * blockDim.x) >> 6);
    const int nchunk = (n_edges + NEPC - 1) / NEPC;
    const int last = n_edges - 1;

    int c = gwave;
    if (c >= nchunk) return;
    auto eclampX = [&](int cc) { int e = cc * NEPC + ecol;      return e < last ? e : last; };
    auto eclampY = [&](int cc) { int e = cc * NEPC + 32 + ecol; return e < last ? e : last; };

    uint2 fAX, fBX, fAY, fBY;
    int sNX = 0, dNX = 0, sNY = 0, dNY = 0;
    {
        const int eX = eclampX(c), eY = eclampY(c);
        if (hi == 0) {
            const int sX = ei[eX], dX = ei[n_edges + eX];
            const int sY = ei[eY], dY = ei[n_edges + eY];
            fAX = nodef[dX]; fBX = nodef[sX];
            fAY = nodef[dY]; fBY = nodef[sY];
            const int e2X = eclampX(c + nwave), e2Y = eclampY(c + nwave);
            sNX = ei[e2X]; dNX = ei[n_edges + e2X];
            sNY = ei[e2Y]; dNY = ei[n_edges + e2Y];
        } else {
            if (IS_MSG) {
                const float4 evX = ((const float4*)eattr)[eX];
                fAX = make_uint2(pk2(evX.x, evX.y), pk2(evX.z, evX.w));
                const float4 evY = ((const float4*)eattr)[eY];
                fAY = make_uint2(pk2(evY.x, evY.y), pk2(evY.z, evY.w));
            } else {
                fAX = ((const uint2*)eattr)[eX];
                fAY = ((const uint2*)eattr)[eY];
            }
            fBX = make_uint2(0x00003c00u, 0u);   // bias word {1.0h, 0h}
            fBY = fBX;
        }
    }

    for (; c < nchunk; ) {
        const int cn = c + nwave;

        const hf8 bfX = frag_from(fAX.x, fAX.y, fBX.x, fBX.y);
        const hf8 bfY = frag_from(fAY.x, fAY.y, fBY.x, fBY.y);

        uint2 nfAX = fAX, nfBX = fBX, nfAY = fAY, nfBY = fBY;
        int sPX = sNX, dPX = dNX, sPY = sNY, dPY = dNY;
        {
            if (hi == 0) {
                nfAX = nodef[dNX]; nfBX = nodef[sNX];
                nfAY = nodef[dNY]; nfBY = nodef[sNY];
                const int e3X = eclampX(cn + nwave), e3Y = eclampY(cn + nwave);
                sPX = ei[e3X]; dPX = ei[n_edges + e3X];
                sPY = ei[e3Y]; dPY = ei[n_edges + e3Y];
            } else {
                const int e2X = eclampX(cn), e2Y = eclampY(cn);
                if (IS_MSG) {
                    const float4 evX = ((const float4*)eattr)[e2X];
                    nfAX = make_uint2(pk2(evX.x, evX.y), pk2(evX.z, evX.w));
                    const float4 evY = ((const float4*)eattr)[e2Y];
                    nfAY = make_uint2(pk2(evY.x, evY.y), pk2(evY.z, evY.w));
                } else {
                    nfAX = ((const uint2*)eattr)[e2X];
                    nfAY = ((const uint2*)eattr)[e2Y];
                }
            }
        }

        f32x16 a0X = {}, a1X = {}, a0Y = {}, a1Y = {};
        a0X = mfma16(wa1[0], bfX, a0X);
        a0Y = mfma16(wa1[0], bfY, a0Y);
        a1X = mfma16(wa1[1], bfX, a1X);
        a1Y = mfma16(wa1[1], bfY, a1Y);

        hf8 f0X, f1X, f2X, f0Y, f1Y, f2Y;
        build_frags(a0X, a1X, hi, f0X, f1X, f2X);
        build_frags(a0Y, a1Y, hi, f0Y, f1Y, f2Y);

        f32x16 c0X = {}, c1X = {}, c0Y = {}, c1Y = {};
        c0X = mfma16(wa2[0][0], f0X, c0X); c0Y = mfma16(wa2[0][0], f0Y, c0Y);
        c1X = mfma16(wa2[1][0], f0X, c1X); c1Y = mfma16(wa2[1][0], f0Y, c1Y);
        c0X = mfma16(wa2[0][1], f1X, c0X); c0Y = mfma16(wa2[0][1], f1Y, c0Y);
        c1X = mfma16(wa2[1][1], f1X, c1X); c1Y = mfma16(wa2[1][1], f1Y, c1Y);
        c0X = mfma16(wa2[0][2], f2X, c0X); c0Y = mfma16(wa2[0][2], f2Y, c0Y);
        c1X = mfma16(wa2[1][2], f2X, c1X); c1Y = mfma16(wa2[1][2], f2Y, c1Y);

        hf8 g0X, g1X, g2X, g0Y, g1Y, g2Y;
        build_frags(c0X, c1X, hi, g0X, g1X, g2X);
        build_frags(c0Y, c1Y, hi, g0Y, g1Y, g2Y);

        f32x16 z0X = {}, z0Y = {};
        z0X = mfma16(wa3[0], g0X, z0X); z0Y = mfma16(wa3[0], g0Y, z0Y);
        z0X = mfma16(wa3[1], g1X, z0X); z0Y = mfma16(wa3[1], g1Y, z0Y);
        z0X = mfma16(wa3[2], g2X, z0X); z0Y = mfma16(wa3[2], g2Y, z0Y);

        if (hi == 0) {
            const int eX = c * NEPC + ecol;
            const int eY = eX + 32;
            if (eX < n_edges) {
                if (IS_MSG)
                    emsg_out[eX] = make_uint2(pk2(z0X[0], z0X[1]), pk2(z0X[2], z0X[3]));
                else
                    out[eX] = 1.f / (1.f + expf(-z0X[0]));
            }
            if (eY < n_edges) {
                if (IS_MSG)
                    emsg_out[eY] = make_uint2(pk2(z0Y[0], z0Y[1]), pk2(z0Y[2], z0Y[3]));
                else
                    out[eY] = 1.f / (1.f + expf(-z0Y[0]));
            }
        }

        fAX = nfAX; fBX = nfBX; fAY = nfAY; fBY = nfBY;
        sNX = sPX; dNX = dPX; sNY = sPY; dNY = dPY;
        c = cn;
    }
}

// ---- node feature packing ----
__global__ __launch_bounds__(256) void nodef_kernel(
    const float* __restrict__ x, uint2* __restrict__ nodef, int n_nodes)
{
    int n = blockIdx.x * blockDim.x + threadIdx.x;
    if (n >= n_nodes) return;
    nodef[n] = make_uint2(pk2(x[n * 3 + 0], x[n * 3 + 1]), pk2(x[n * 3 + 2], 0.f));
}

// ---- A: per-(tile,bucket) counts (LDS atomics only) ----
__global__ __launch_bounds__(TS) void count_kernel(
    const int* __restrict__ dstp, unsigned* __restrict__ tilecnt, int n_edges)
{
    __shared__ unsigned lc[NBMAX];
    const int tid = threadIdx.x;
    if (tid < NBMAX) lc[tid] = 0u;
    __syncthreads();
    const int e = blockIdx.x * TS + tid;
    if (e < n_edges) atomicAdd(&lc[((unsigned)dstp[e]) >> 12], 1u);
    __syncthreads();
    if (tid < NBMAX) tilecnt[(size_t)blockIdx.x * NBMAX + tid] = lc[tid];
}

// ---- B: per-bucket exclusive prefix over tiles (in place) + totals ----
__global__ __launch_bounds__(1024) void scan_kernel(
    unsigned* __restrict__ tilecnt, unsigned* __restrict__ totals, int ntiles)
{
    __shared__ unsigned buf[1024];
    const int b = blockIdx.x;
    const int tid = threadIdx.x;
    unsigned carry = 0;
    for (int base = 0; base < ntiles; base += 1024) {
        const int i = base + tid;
        const unsigned v = (i < ntiles) ? tilecnt[(size_t)i * NBMAX + b] : 0u;
        buf[tid] = v;
        __syncthreads();
        for (int off = 1; off < 1024; off <<= 1) {
            const unsigned t = (tid >= off) ? buf[tid - off] : 0u;
            __syncthreads();
            buf[tid] += t;
            __syncthreads();
        }
        if (i < ntiles) tilecnt[(size_t)i * NBMAX + b] = (buf[tid] - v) + carry;
        carry += buf[1023];
        __syncthreads();
    }
    if (tid == 0) totals[b] = carry;
}

// ---- C: exclusive scan of bucket totals ----
__global__ __launch_bounds__(64) void base_kernel(
    const unsigned* __restrict__ totals, unsigned* __restrict__ bases, int nbins)
{
    if (threadIdx.x == 0) {
        unsigned run = 0;
        for (int i = 0; i < nbins; ++i) { bases[i] = run; run += totals[i]; }
    }
}

// ---- D: multisplit scatter (SoA output), static offsets ----
__global__ __launch_bounds__(TS) void split_kernel(
    const int* __restrict__ dstp,
    const uint2* __restrict__ emsg,
    const unsigned* __restrict__ tilecnt,   // exclusive per-tile offsets
    const unsigned* __restrict__ bases,
    unsigned* __restrict__ bd,              // dst per record, bucket-contiguous
    uint2* __restrict__ bm,                 // msg per record
    int n_edges, int nbins)
{
    __shared__ unsigned lcnt[NBMAX], loff[NBMAX], gbase[NBMAX];
    __shared__ unsigned stage[TS * 3];      // 12KB
    const int tid = threadIdx.x;
    const int e = blockIdx.x * TS + tid;
    const bool valid = e < n_edges;

    if (tid < NBMAX) lcnt[tid] = 0u;
    __syncthreads();

    unsigned d = 0, b = 0, slot = 0; uint2 m = make_uint2(0u, 0u);
    if (valid) {
        d = (unsigned)dstp[e];
        m = emsg[e];
        b = d >> 12;
        slot = atomicAdd(&lcnt[b], 1u);
    }
    __syncthreads();

    if (tid < NBMAX && tid < (unsigned)nbins) {
        gbase[tid] = bases[tid] + tilecnt[(size_t)blockIdx.x * NBMAX + tid];
    }
    if (tid == 0) {
        unsigned run = 0;
        for (int i = 0; i < nbins; ++i) { loff[i] = run; run += lcnt[i]; }
    }
    __syncthreads();

    if (valid) {
        const unsigned p = (loff[b] + slot) * 3;
        stage[p] = d; stage[p + 1] = m.x; stage[p + 2] = m.y;
    }
    __syncthreads();

    const int total = min(TS, n_edges - blockIdx.x * TS);
    if (tid < total) {
        const unsigned dd = stage[tid * 3];
        const unsigned bb = dd >> 12;
        const unsigned gpos = gbase[bb] + ((unsigned)tid - loff[bb]);
        bd[gpos] = dd;
        bm[gpos] = make_uint2(stage[tid * 3 + 1], stage[tid * 3 + 2]);
    }
}

// ---- E: dense per-(bucket,slice) scan -> f16x4 LDS bins via ds_pk_add_f16,
//      x4 unrolled (4 dense loads in flight per thread-iteration) ----
typedef _Float16 hf2 __attribute__((ext_vector_type(2)));
__device__ __forceinline__ void pk_accum(unsigned* __restrict__ bin,
                                         unsigned d, uint2 m) {
    const unsigned laddr =
        (unsigned)(reinterpret_cast<uintptr_t>(&bin[(d & (BS - 1)) * 2]));
    asm volatile("ds_pk_add_f16 %0, %1" :: "v"(laddr), "v"(m.x) : "memory");
    asm volatile("ds_pk_add_f16 %0, %1 offset:4" :: "v"(laddr), "v"(m.y) : "memory");
}

__global__ __launch_bounds__(1024) void accum_kernel(
    const unsigned* __restrict__ bd,
    const uint2* __restrict__ bm,
    const unsigned* __restrict__ totals,
    const unsigned* __restrict__ bases,
    uint2* __restrict__ scratch,      // [B*S][BS] f16x4 partials
    int S)
{
    __shared__ unsigned bin[BS * 2];  // 32 KB, f16x4 per node
    const int bid = blockIdx.x / S, s = blockIdx.x % S;
    const int tid = threadIdx.x;

#pragma unroll
    for (int i = 0; i < (BS * 2) / 1024; ++i)
        bin[tid + i * 1024] = 0u;
    __syncthreads();

    const unsigned start = bases[bid], len = totals[bid];
    const unsigned r0 = start + (unsigned)((unsigned long long)len * s / S);
    const unsigned r1 = start + (unsigned)((unsigned long long)len * (s + 1) / S);

    unsigned r = r0 + tid;
    for (; r + 3072 < r1; r += 4096) {
        const unsigned d0 = bd[r], d1 = bd[r + 1024], d2 = bd[r + 2048], d3 = bd[r + 3072];
        const uint2 m0 = bm[r], m1 = bm[r + 1024], m2 = bm[r + 2048], m3 = bm[r + 3072];
        pk_accum(bin, d0, m0);
        pk_accum(bin, d1, m1);
        pk_accum(bin, d2, m2);
        pk_accum(bin, d3, m3);
    }
    for (; r < r1; r += 1024)
        pk_accum(bin, bd[r], bm[r]);
    __syncthreads();

    uint2* dst = scratch + (size_t)(bid * S + s) * BS;
    const uint2* srcb = (const uint2*)bin;
#pragma unroll
    for (int i = 0; i < BS / 1024; ++i)
        dst[tid + i * 1024] = srcb[tid + i * 1024];
}

// ---- F: f32 sum of S f16x4 partials -> aggr f32[N][4] ----
__global__ __launch_bounds__(256) void reduce_kernel(
    const uint2* __restrict__ scratch,
    float* __restrict__ aggr,
    int n_nodes, int S)
{
    int n = blockIdx.x * blockDim.x + threadIdx.x;
    if (n >= n_nodes) return;
    const int b = n / BS, nl = n % BS;
    float4 acc = make_float4(0.f, 0.f, 0.f, 0.f);
    for (int w = 0; w < S; ++w) {
        const uint2 v = scratch[(size_t)(b * S + w) * BS + nl];
        const hf2 lo = __builtin_bit_cast(hf2, v.x);
        const hf2 hi = __builtin_bit_cast(hf2, v.y);
        acc.x += (float)lo.x; acc.y += (float)lo.y;
        acc.z += (float)hi.x; acc.w += (float)hi.y;
    }
    *(float4*)(aggr + (size_t)n * 4) = acc;
}

template<int IN, int OUT, bool RELU>
__device__ __forceinline__ void dense(const float* __restrict__ w,
                                      const float* __restrict__ b,
                                      const float* in, float* out) {
#pragma unroll
    for (int j = 0; j < OUT; ++j) {
        float acc = b[j];
#pragma unroll
        for (int k = 0; k < IN; ++k) acc = fmaf(w[j * IN + k], in[k], acc);
        out[j] = RELU ? fmaxf(acc, 0.f) : acc;
    }
}

__global__ __launch_bounds__(256) void node_kernel(
    const float* __restrict__ x,
    const float* __restrict__ aggr,
    const float* __restrict__ w1, const float* __restrict__ b1,
    const float* __restrict__ w2, const float* __restrict__ b2,
    const float* __restrict__ w3, const float* __restrict__ b3,
    uint2* __restrict__ xth,
    int n_nodes)
{
    int n = blockIdx.x * blockDim.x + threadIdx.x;
    if (n >= n_nodes) return;

    float in[7];
    in[0] = x[n * 3 + 0]; in[1] = x[n * 3 + 1]; in[2] = x[n * 3 + 2];
    const float4 ag = *(const float4*)(aggr + (size_t)n * 4);
    in[3] = ag.x; in[4] = ag.y; in[5] = ag.z; in[6] = ag.w;

    float h1[40], h2[40], o[3];
    dense<7, 40, true >(w1, b1, in, h1);
    dense<40, 40, true>(w2, b2, h1, h2);
    dense<40, 3, false>(w3, b3, h2, o);

    xth[n] = make_uint2(pk2(o[0], o[1]), pk2(o[2], 0.f));
}

extern "C" void kernel_launch(void* const* d_in, const int* in_sizes, int n_in,
                              void* d_out, int out_size, void* d_ws, size_t ws_size,
                              hipStream_t stream) {
    const float* x  = (const float*)d_in[0];
    const int*   ei = (const int*)d_in[1];   // int64 delivered as int32
    const float* ea = (const float*)d_in[2];

    const float* r1_w1 = (const float*)d_in[3];
    const float* r1_b1 = (const float*)d_in[4];
    const float* r1_w2 = (const float*)d_in[5];
    const float* r1_b2 = (const float*)d_in[6];
    const float* r1_w3 = (const float*)d_in[7];
    const float* r1_b3 = (const float*)d_in[8];

    const float* o_w1 = (const float*)d_in[9];
    const float* o_b1 = (const float*)d_in[10];
    const float* o_w2 = (const float*)d_in[11];
    const float* o_b2 = (const float*)d_in[12];
    const float* o_w3 = (const float*)d_in[13];
    const float* o_b3 = (const float*)d_in[14];

    const float* r2_w1 = (const float*)d_in[15];
    const float* r2_b1 = (const float*)d_in[16];
    const float* r2_w2 = (const float*)d_in[17];
    const float* r2_b2 = (const float*)d_in[18];
    const float* r2_w3 = (const float*)d_in[19];
    const float* r2_b3 = (const float*)d_in[20];

    const int n_nodes = in_sizes[0] / 3;
    const int n_edges = in_sizes[2] / 4;
    const int B = (n_nodes + BS - 1) / BS;        // 25 buckets
    const int ntiles = (n_edges + TS - 1) / TS;   // split tiles

    // ws layout:
    //  nodef uint2[N] | aggr f32[N*4] | emsg uint2[E] | bd u32[E] | bm uint2[E] |
    //  totals u32[NBMAX] | bases u32[NBMAX] | tilecnt u32[ntiles*NBMAX] |
    //  wtab1 uint4[NFRAG*64] | wtab2 uint4[NFRAG*64] | scratch uint2[B*S*BS]
    uint2*    nodef   = (uint2*)d_ws;
    float*    aggr    = (float*)(nodef + n_nodes);
    uint2*    emsg    = (uint2*)(aggr + (size_t)n_nodes * 4);
    unsigned* bd      = (unsigned*)(emsg + n_edges);
    uint2*    bm      = (uint2*)(bd + n_edges);
    unsigned* totals  = (unsigned*)(bm + n_edges);
    unsigned* bases   = totals + NBMAX;
    unsigned* tilecnt = bases + NBMAX;
    uint4*    wtab1   = (uint4*)(tilecnt + (size_t)ntiles * NBMAX);
    uint4*    wtab2   = wtab1 + NFRAG * 64;
    uint2*    scratch = (uint2*)(wtab2 + NFRAG * 64);

    const size_t fixed_bytes = (char*)scratch - (char*)d_ws;
    int S = 16;                                   // slices per bucket
    while (S > 4 && ws_size < fixed_bytes + (size_t)B * S * BS * sizeof(uint2))
        S >>= 1;

    const int eb = 1024;                          // 4 blocks/CU offered
    const int nb = (n_nodes + 255) / 256;

    wprep_kernel<<<2, 64, 0, stream>>>(r1_w1, r1_b1, r1_w2, r1_b2, r1_w3, r1_b3,
                                       r2_w1, r2_b1, r2_w2, r2_b2, r2_w3, r2_b3,
                                       wtab1, wtab2);

    nodef_kernel<<<nb, 256, 0, stream>>>(x, nodef, n_nodes);

    edge_kernel<true><<<eb, 256, 0, stream>>>(nodef, ei, (const void*)ea,
        wtab1, emsg, nullptr, n_edges);

    count_kernel<<<ntiles, TS, 0, stream>>>(ei + n_edges, tilecnt, n_edges);

    scan_kernel<<<B, 1024, 0, stream>>>(tilecnt, totals, ntiles);

    base_kernel<<<1, 64, 0, stream>>>(totals, bases, B);

    split_kernel<<<ntiles, TS, 0, stream>>>(ei + n_edges, emsg, tilecnt, bases,
                                            bd, bm, n_edges, B);

    accum_kernel<<<B * S, 1024, 0, stream>>>(bd, bm, totals, bases, scratch, S);

    reduce_kernel<<<nb, 256, 0, stream>>>(scratch, aggr, n_nodes, S);

    node_kernel<<<nb, 256, 0, stream>>>(x, aggr,
        o_w1, o_b1, o_w2, o_b2, o_w3, o_b3, nodef, n_nodes);

    edge_kernel<false><<<eb, 256, 0, stream>>>(nodef, ei, (const void*)emsg,
        wtab2, nullptr, (float*)d_out, n_edges);
}

// Round 17
// 168.745 us; speedup vs baseline: 3.7135x; 1.0460x over previous
//
#include <hip/hip_runtime.h>
#include <math.h>

// Interaction Network — LDS-free MFMA edge kernels (ILP x2, wtab prologue,
// permlane32_swap transitions) + atomic-free multisplit aggregation,
// ds_pk_add_f16 bins, reduce fused into node kernel.
// Layer-1 K layout: k0-2 xd | 3 pad | 4-6 xs | 7 pad | 8-11 ea/msg | 12 bias | 13-15 pad
// C layout (HW-verified): col=lane&31, row=(reg&3)+8*(reg>>2)+4*(lane>>5).
// V_PERMLANE32_SWAP_B32(vdst,src): vdst rows 32-63 <-> src rows 0-31, i.e.
//  ret.x = {lo: own A, hi: B from lane-32}; ret.y = {lo: A from lane+32, hi: own B}.

typedef __fp16 hf8 __attribute__((ext_vector_type(8)));
typedef _Float16 f16x2 __attribute__((ext_vector_type(2)));
typedef float f32x16 __attribute__((ext_vector_type(16)));
typedef unsigned u32x2 __attribute__((ext_vector_type(2)));
typedef unsigned u32x4 __attribute__((ext_vector_type(4)));

#define NEPC  64   // edges per wave-chunk (two MFMA column tiles X/Y)
#define BS    4096 // nodes per aggregation bin
#define NBMAX 32   // max buckets (N=100K -> 25)
#define TS    1024 // split tile size
#define NFRAG 11   // weight fragments per edge MLP

__device__ __forceinline__ f32x16 mfma16(hf8 a, hf8 b, f32x16 c) {
    return __builtin_amdgcn_mfma_f32_32x32x16_f16(a, b, c, 0, 0, 0);
}
__device__ __forceinline__ unsigned pk2(float a, float b) {
    return __builtin_bit_cast(unsigned, __builtin_amdgcn_cvt_pkrtz(a, b));
}
__device__ __forceinline__ unsigned pk2_relu(float a, float b) {
    return __builtin_bit_cast(unsigned,
        __builtin_amdgcn_cvt_pkrtz(fmaxf(a, 0.f), fmaxf(b, 0.f)));
}
__device__ __forceinline__ u32x2 pl32swap(unsigned a, unsigned b) {
    return __builtin_amdgcn_permlane32_swap(a, b, false, false);
}
__device__ __forceinline__ hf8 frag_from(unsigned a, unsigned b, unsigned c, unsigned d) {
    u32x4 v = {a, b, c, d};
    return __builtin_bit_cast(hf8, v);
}

// Build the 3 B-fragments (K=48: ch0..39 + bias@40) from C-layout accumulators
// t0 (ch 0..31) and t1 (ch 32..39), relu applied.
// Word wj on a LO lane holds ch{2j,2j+1} of {0..7}x4-blocks; desired:
//  F0 w0={lo:w0,hi:p2} w1={lo:w1,hi:p3} w2={lo:p0,hi:w2} w3={lo:p1,hi:w3}
//  -> r=swap(w0,w2): r.x={lo:w0,hi:p2}, r.y={lo:p0,hi:w2}.
__device__ __forceinline__ void build_frags(const f32x16& t0, const f32x16& t1,
                                            int hi, hf8& F0, hf8& F1, hf8& F2) {
    const unsigned w0 = pk2_relu(t0[0],  t0[1]);
    const unsigned w1 = pk2_relu(t0[2],  t0[3]);
    const unsigned w2 = pk2_relu(t0[4],  t0[5]);
    const unsigned w3 = pk2_relu(t0[6],  t0[7]);
    const unsigned w4 = pk2_relu(t0[8],  t0[9]);
    const unsigned w5 = pk2_relu(t0[10], t0[11]);
    const unsigned w6 = pk2_relu(t0[12], t0[13]);
    const unsigned w7 = pk2_relu(t0[14], t0[15]);
    const unsigned w8 = pk2_relu(t1[0],  t1[1]);
    const unsigned w9 = pk2_relu(t1[2],  t1[3]);
    const u32x2 r0 = pl32swap(w0, w2);
    const u32x2 r1 = pl32swap(w1, w3);
    const u32x2 r2 = pl32swap(w4, w6);
    const u32x2 r3 = pl32swap(w5, w7);
    const u32x2 r4 = pl32swap(w8, 0u);   // .y = {lo: partner w8, hi: 0}
    const u32x2 r5 = pl32swap(w9, 0u);
    F0 = frag_from(r0.x, r1.x, r0.y, r1.y);
    F1 = frag_from(r2.x, r3.x, r2.y, r3.y);
    F2 = frag_from(hi ? 0x00003c00u : w8, hi ? 0u : w9, r4.y, r5.y);
}

// hidden-layer A fragment (IN=40 + bias at k=40), runtime OUT
__device__ hf8 load_wfrag40(const float* __restrict__ w, const float* __restrict__ b,
                            int OUT, int mt, int ks, int lane) {
    const int r = mt * 32 + (lane & 31);
    const int kbase = ks * 16 + ((lane >> 5) & 1) * 8;
    hf8 f;
#pragma unroll
    for (int j = 0; j < 8; ++j) {
        const int k = kbase + j;
        float v = 0.f;
        if (r < OUT) {
            if (k < 40) v = w[r * 40 + k];
            else if (k == 40) v = b[r];
        }
        f[j] = (__fp16)v;
    }
    return f;
}

// layer-1 A fragment, padded K map (IN fixed at 10)
__device__ hf8 load_wfrag_l1(const float* __restrict__ w, const float* __restrict__ b,
                             int mt, int lane) {
    const int r = mt * 32 + (lane & 31);
    const int kbase = ((lane >> 5) & 1) * 8;
    hf8 f;
#pragma unroll
    for (int j = 0; j < 8; ++j) {
        const int k = kbase + j;
        float v = 0.f;
        if (r < 40) {
            int src = -1;
            if (k < 3) src = k;                       // xd
            else if (k >= 4 && k < 7) src = k - 1;    // xs
            else if (k >= 8 && k < 12) src = k - 2;   // ea/msg
            if (src >= 0) v = w[r * 10 + src];
            else if (k == 12) v = b[r];
        }
        f[j] = (__fp16)v;
    }
    return f;
}

// ---- weight fragment table prep (both MLPs in one launch; block 0=R1, 1=R2) ----
__global__ __launch_bounds__(64) void wprep_kernel(
    const float* __restrict__ a_w1, const float* __restrict__ a_b1,
    const float* __restrict__ a_w2, const float* __restrict__ a_b2,
    const float* __restrict__ a_w3, const float* __restrict__ a_b3,
    const float* __restrict__ b_w1, const float* __restrict__ b_b1,
    const float* __restrict__ b_w2, const float* __restrict__ b_b2,
    const float* __restrict__ b_w3, const float* __restrict__ b_b3,
    uint4* __restrict__ tab1, uint4* __restrict__ tab2)
{
    const int lane = threadIdx.x;
    const bool second = blockIdx.x == 1;
    const float* w1 = second ? b_w1 : a_w1; const float* b1 = second ? b_b1 : a_b1;
    const float* w2 = second ? b_w2 : a_w2; const float* b2 = second ? b_b2 : a_b2;
    const float* w3 = second ? b_w3 : a_w3; const float* b3 = second ? b_b3 : a_b3;
    uint4* tab = second ? tab2 : tab1;
    const int out3 = second ? 1 : 4;
#pragma unroll
    for (int t = 0; t < 2; ++t)
        tab[t * 64 + lane] = __builtin_bit_cast(uint4, load_wfrag_l1(w1, b1, t, lane));
#pragma unroll
    for (int t = 0; t < 2; ++t)
#pragma unroll
        for (int s = 0; s < 3; ++s)
            tab[(2 + t * 3 + s) * 64 + lane] =
                __builtin_bit_cast(uint4, load_wfrag40(w2, b2, 40, t, s, lane));
#pragma unroll
    for (int s = 0; s < 3; ++s)
        tab[(8 + s) * 64 + lane] =
            __builtin_bit_cast(uint4, load_wfrag40(w3, b3, out3, 0, s, lane));
}

template<bool IS_MSG>
__global__ __launch_bounds__(256, 3) void edge_kernel(
    const uint2* __restrict__ nodef,
    const int*   __restrict__ ei,
    const void*  __restrict__ eattr,
    const uint4* __restrict__ wtab,   // precomputed fragments
    uint2* __restrict__ emsg_out,
    float* __restrict__ out,
    int n_edges)
{
    const int lane = threadIdx.x & 63;
    const int ecol = lane & 31;
    const int hi = lane >> 5;

    // prologue: 11 coalesced 16B fragment loads
    hf8 wa1[2], wa2[2][3], wa3[3];
    wa1[0] = __builtin_bit_cast(hf8, wtab[0 * 64 + lane]);
    wa1[1] = __builtin_bit_cast(hf8, wtab[1 * 64 + lane]);
#pragma unroll
    for (int t = 0; t < 2; ++t)
#pragma unroll
        for (int s = 0; s < 3; ++s)
            wa2[t][s] = __builtin_bit_cast(hf8, wtab[(2 + t * 3 + s) * 64 + lane]);
#pragma unroll
    for (int s = 0; s < 3; ++s)
        wa3[s] = __builtin_bit_cast(hf8, wtab[(8 + s) * 64 + lane]);

    const int gwave = (int)((blockIdx.x * blockDim.x + threadIdx.x) >> 6);
    const int nwave = (int)((gridDim.x * blockDim.x) >> 6);
    const int nchunk = (n_edges + NEPC - 1) / NEPC;
    const int last = n_edges - 1;

    int c = gwave;
    if (c >= nchunk) return;
    auto eclampX = [&](int cc) { int e = cc * NEPC + ecol;      return e < last ? e : last; };
    auto eclampY = [&](int cc) { int e = cc * NEPC + 32 + ecol; return e < last ? e : last; };

    uint2 fAX, fBX, fAY, fBY;
    int sNX = 0, dNX = 0, sNY = 0, dNY = 0;
    {
        const int eX = eclampX(c), eY = eclampY(c);
        if (hi == 0) {
            const int sX = ei[eX], dX = ei[n_edges + eX];
            const int sY = ei[eY], dY = ei[n_edges + eY];
            fAX = nodef[dX]; fBX = nodef[sX];
            fAY = nodef[dY]; fBY = nodef[sY];
            const int e2X = eclampX(c + nwave), e2Y = eclampY(c + nwave);
            sNX = ei[e2X]; dNX = ei[n_edges + e2X];
            sNY = ei[e2Y]; dNY = ei[n_edges + e2Y];
        } else {
            if (IS_MSG) {
                const float4 evX = ((const float4*)eattr)[eX];
                fAX = make_uint2(pk2(evX.x, evX.y), pk2(evX.z, evX.w));
                const float4 evY = ((const float4*)eattr)[eY];
                fAY = make_uint2(pk2(evY.x, evY.y), pk2(evY.z, evY.w));
            } else {
                fAX = ((const uint2*)eattr)[eX];
                fAY = ((const uint2*)eattr)[eY];
            }
            fBX = make_uint2(0x00003c00u, 0u);   // bias word {1.0h, 0h}
            fBY = fBX;
        }
    }

    for (; c < nchunk; ) {
        const int cn = c + nwave;

        const hf8 bfX = frag_from(fAX.x, fAX.y, fBX.x, fBX.y);
        const hf8 bfY = frag_from(fAY.x, fAY.y, fBY.x, fBY.y);

        uint2 nfAX = fAX, nfBX = fBX, nfAY = fAY, nfBY = fBY;
        int sPX = sNX, dPX = dNX, sPY = sNY, dPY = dNY;
        {
            if (hi == 0) {
                nfAX = nodef[dNX]; nfBX = nodef[sNX];
                nfAY = nodef[dNY]; nfBY = nodef[sNY];
                const int e3X = eclampX(cn + nwave), e3Y = eclampY(cn + nwave);
                sPX = ei[e3X]; dPX = ei[n_edges + e3X];
                sPY = ei[e3Y]; dPY = ei[n_edges + e3Y];
            } else {
                const int e2X = eclampX(cn), e2Y = eclampY(cn);
                if (IS_MSG) {
                    const float4 evX = ((const float4*)eattr)[e2X];
                    nfAX = make_uint2(pk2(evX.x, evX.y), pk2(evX.z, evX.w));
                    const float4 evY = ((const float4*)eattr)[e2Y];
                    nfAY = make_uint2(pk2(evY.x, evY.y), pk2(evY.z, evY.w));
                } else {
                    nfAX = ((const uint2*)eattr)[e2X];
                    nfAY = ((const uint2*)eattr)[e2Y];
                }
            }
        }

        f32x16 a0X = {}, a1X = {}, a0Y = {}, a1Y = {};
        a0X = mfma16(wa1[0], bfX, a0X);
        a0Y = mfma16(wa1[0], bfY, a0Y);
        a1X = mfma16(wa1[1], bfX, a1X);
        a1Y = mfma16(wa1[1], bfY, a1Y);

        hf8 f0X, f1X, f2X, f0Y, f1Y, f2Y;
        build_frags(a0X, a1X, hi, f0X, f1X, f2X);
        build_frags(a0Y, a1Y, hi, f0Y, f1Y, f2Y);

        f32x16 c0X = {}, c1X = {}, c0Y = {}, c1Y = {};
        c0X = mfma16(wa2[0][0], f0X, c0X); c0Y = mfma16(wa2[0][0], f0Y, c0Y);
        c1X = mfma16(wa2[1][0], f0X, c1X); c1Y = mfma16(wa2[1][0], f0Y, c1Y);
        c0X = mfma16(wa2[0][1], f1X, c0X); c0Y = mfma16(wa2[0][1], f1Y, c0Y);
        c1X = mfma16(wa2[1][1], f1X, c1X); c1Y = mfma16(wa2[1][1], f1Y, c1Y);
        c0X = mfma16(wa2[0][2], f2X, c0X); c0Y = mfma16(wa2[0][2], f2Y, c0Y);
        c1X = mfma16(wa2[1][2], f2X, c1X); c1Y = mfma16(wa2[1][2], f2Y, c1Y);

        hf8 g0X, g1X, g2X, g0Y, g1Y, g2Y;
        build_frags(c0X, c1X, hi, g0X, g1X, g2X);
        build_frags(c0Y, c1Y, hi, g0Y, g1Y, g2Y);

        f32x16 z0X = {}, z0Y = {};
        z0X = mfma16(wa3[0], g0X, z0X); z0Y = mfma16(wa3[0], g0Y, z0Y);
        z0X = mfma16(wa3[1], g1X, z0X); z0Y = mfma16(wa3[1], g1Y, z0Y);
        z0X = mfma16(wa3[2], g2X, z0X); z0Y = mfma16(wa3[2], g2Y, z0Y);

        if (hi == 0) {
            const int eX = c * NEPC + ecol;
            const int eY = eX + 32;
            if (eX < n_edges) {
                if (IS_MSG)
                    emsg_out[eX] = make_uint2(pk2(z0X[0], z0X[1]), pk2(z0X[2], z0X[3]));
                else
                    out[eX] = 1.f / (1.f + expf(-z0X[0]));
            }
            if (eY < n_edges) {
                if (IS_MSG)
                    emsg_out[eY] = make_uint2(pk2(z0Y[0], z0Y[1]), pk2(z0Y[2], z0Y[3]));
                else
                    out[eY] = 1.f / (1.f + expf(-z0Y[0]));
            }
        }

        fAX = nfAX; fBX = nfBX; fAY = nfAY; fBY = nfBY;
        sNX = sPX; dNX = dPX; sNY = sPY; dNY = dPY;
        c = cn;
    }
}

// ---- node feature packing ----
__global__ __launch_bounds__(256) void nodef_kernel(
    const float* __restrict__ x, uint2* __restrict__ nodef, int n_nodes)
{
    int n = blockIdx.x * blockDim.x + threadIdx.x;
    if (n >= n_nodes) return;
    nodef[n] = make_uint2(pk2(x[n * 3 + 0], x[n * 3 + 1]), pk2(x[n * 3 + 2], 0.f));
}

// ---- A: per-(tile,bucket) counts (LDS atomics only) ----
__global__ __launch_bounds__(TS) void count_kernel(
    const int* __restrict__ dstp, unsigned* __restrict__ tilecnt, int n_edges)
{
    __shared__ unsigned lc[NBMAX];
    const int tid = threadIdx.x;
    if (tid < NBMAX) lc[tid] = 0u;
    __syncthreads();
    const int e = blockIdx.x * TS + tid;
    if (e < n_edges) atomicAdd(&lc[((unsigned)dstp[e]) >> 12], 1u);
    __syncthreads();
    if (tid < NBMAX) tilecnt[(size_t)blockIdx.x * NBMAX + tid] = lc[tid];
}

// ---- B: per-bucket exclusive prefix over tiles (in place) + totals ----
__global__ __launch_bounds__(1024) void scan_kernel(
    unsigned* __restrict__ tilecnt, unsigned* __restrict__ totals, int ntiles)
{
    __shared__ unsigned buf[1024];
    const int b = blockIdx.x;
    const int tid = threadIdx.x;
    unsigned carry = 0;
    for (int base = 0; base < ntiles; base += 1024) {
        const int i = base + tid;
        const unsigned v = (i < ntiles) ? tilecnt[(size_t)i * NBMAX + b] : 0u;
        buf[tid] = v;
        __syncthreads();
        for (int off = 1; off < 1024; off <<= 1) {
            const unsigned t = (tid >= off) ? buf[tid - off] : 0u;
            __syncthreads();
            buf[tid] += t;
            __syncthreads();
        }
        if (i < ntiles) tilecnt[(size_t)i * NBMAX + b] = (buf[tid] - v) + carry;
        carry += buf[1023];
        __syncthreads();
    }
    if (tid == 0) totals[b] = carry;
}

// ---- C: exclusive scan of bucket totals ----
__global__ __launch_bounds__(64) void base_kernel(
    const unsigned* __restrict__ totals, unsigned* __restrict__ bases, int nbins)
{
    if (threadIdx.x == 0) {
        unsigned run = 0;
        for (int i = 0; i < nbins; ++i) { bases[i] = run; run += totals[i]; }
    }
}

// ---- D: multisplit scatter (SoA output), static offsets ----
__global__ __launch_bounds__(TS) void split_kernel(
    const int* __restrict__ dstp,
    const uint2* __restrict__ emsg,
    const unsigned* __restrict__ tilecnt,   // exclusive per-tile offsets
    const unsigned* __restrict__ bases,
    unsigned* __restrict__ bd,              // dst per record, bucket-contiguous
    uint2* __restrict__ bm,                 // msg per record
    int n_edges, int nbins)
{
    __shared__ unsigned lcnt[NBMAX], loff[NBMAX], gbase[NBMAX];
    __shared__ unsigned stage[TS * 3];      // 12KB
    const int tid = threadIdx.x;
    const int e = blockIdx.x * TS + tid;
    const bool valid = e < n_edges;

    if (tid < NBMAX) lcnt[tid] = 0u;
    __syncthreads();

    unsigned d = 0, b = 0, slot = 0; uint2 m = make_uint2(0u, 0u);
    if (valid) {
        d = (unsigned)dstp[e];
        m = emsg[e];
        b = d >> 12;
        slot = atomicAdd(&lcnt[b], 1u);
    }
    __syncthreads();

    if (tid < NBMAX && tid < (unsigned)nbins) {
        gbase[tid] = bases[tid] + tilecnt[(size_t)blockIdx.x * NBMAX + tid];
    }
    if (tid == 0) {
        unsigned run = 0;
        for (int i = 0; i < nbins; ++i) { loff[i] = run; run += lcnt[i]; }
    }
    __syncthreads();

    if (valid) {
        const unsigned p = (loff[b] + slot) * 3;
        stage[p] = d; stage[p + 1] = m.x; stage[p + 2] = m.y;
    }
    __syncthreads();

    const int total = min(TS, n_edges - blockIdx.x * TS);
    if (tid < total) {
        const unsigned dd = stage[tid * 3];
        const unsigned bb = dd >> 12;
        const unsigned gpos = gbase[bb] + ((unsigned)tid - loff[bb]);
        bd[gpos] = dd;
        bm[gpos] = make_uint2(stage[tid * 3 + 1], stage[tid * 3 + 2]);
    }
}

// ---- E: dense per-(bucket,slice) scan -> f16x4 LDS bins via ds_pk_add_f16,
//      x4 unrolled (4 dense loads in flight per thread-iteration) ----
typedef _Float16 hf2 __attribute__((ext_vector_type(2)));
__device__ __forceinline__ void pk_accum(unsigned* __restrict__ bin,
                                         unsigned d, uint2 m) {
    const unsigned laddr =
        (unsigned)(reinterpret_cast<uintptr_t>(&bin[(d & (BS - 1)) * 2]));
    asm volatile("ds_pk_add_f16 %0, %1" :: "v"(laddr), "v"(m.x) : "memory");
    asm volatile("ds_pk_add_f16 %0, %1 offset:4" :: "v"(laddr), "v"(m.y) : "memory");
}

__global__ __launch_bounds__(1024) void accum_kernel(
    const unsigned* __restrict__ bd,
    const uint2* __restrict__ bm,
    const unsigned* __restrict__ totals,
    const unsigned* __restrict__ bases,
    uint2* __restrict__ scratch,      // [B*S][BS] f16x4 partials
    int S)
{
    __shared__ unsigned bin[BS * 2];  // 32 KB, f16x4 per node
    const int bid = blockIdx.x / S, s = blockIdx.x % S;
    const int tid = threadIdx.x;

#pragma unroll
    for (int i = 0; i < (BS * 2) / 1024; ++i)
        bin[tid + i * 1024] = 0u;
    __syncthreads();

    const unsigned start = bases[bid], len = totals[bid];
    const unsigned r0 = start + (unsigned)((unsigned long long)len * s / S);
    const unsigned r1 = start + (unsigned)((unsigned long long)len * (s + 1) / S);

    unsigned r = r0 + tid;
    for (; r + 3072 < r1; r += 4096) {
        const unsigned d0 = bd[r], d1 = bd[r + 1024], d2 = bd[r + 2048], d3 = bd[r + 3072];
        const uint2 m0 = bm[r], m1 = bm[r + 1024], m2 = bm[r + 2048], m3 = bm[r + 3072];
        pk_accum(bin, d0, m0);
        pk_accum(bin, d1, m1);
        pk_accum(bin, d2, m2);
        pk_accum(bin, d3, m3);
    }
    for (; r < r1; r += 1024)
        pk_accum(bin, bd[r], bm[r]);
    __syncthreads();

    uint2* dst = scratch + (size_t)(bid * S + s) * BS;
    const uint2* srcb = (const uint2*)bin;
#pragma unroll
    for (int i = 0; i < BS / 1024; ++i)
        dst[tid + i * 1024] = srcb[tid + i * 1024];
}

template<int IN, int OUT, bool RELU>
__device__ __forceinline__ void dense(const float* __restrict__ w,
                                      const float* __restrict__ b,
                                      const float* in, float* out) {
#pragma unroll
    for (int j = 0; j < OUT; ++j) {
        float acc = b[j];
#pragma unroll
        for (int k = 0; k < IN; ++k) acc = fmaf(w[j * IN + k], in[k], acc);
        out[j] = RELU ? fmaxf(acc, 0.f) : acc;
    }
}

// ---- node update, with slice-reduction fused (reads S f16x4 partials) ----
__global__ __launch_bounds__(256) void node_kernel(
    const float* __restrict__ x,
    const uint2* __restrict__ scratch,
    const float* __restrict__ w1, const float* __restrict__ b1,
    const float* __restrict__ w2, const float* __restrict__ b2,
    const float* __restrict__ w3, const float* __restrict__ b3,
    uint2* __restrict__ xth,
    int n_nodes, int S)
{
    int n = blockIdx.x * blockDim.x + threadIdx.x;
    if (n >= n_nodes) return;

    const int b = n / BS, nl = n % BS;
    float4 ag = make_float4(0.f, 0.f, 0.f, 0.f);
    for (int w = 0; w < S; ++w) {
        const uint2 v = scratch[(size_t)(b * S + w) * BS + nl];
        const hf2 lo = __builtin_bit_cast(hf2, v.x);
        const hf2 hi = __builtin_bit_cast(hf2, v.y);
        ag.x += (float)lo.x; ag.y += (float)lo.y;
        ag.z += (float)hi.x; ag.w += (float)hi.y;
    }

    float in[7];
    in[0] = x[n * 3 + 0]; in[1] = x[n * 3 + 1]; in[2] = x[n * 3 + 2];
    in[3] = ag.x; in[4] = ag.y; in[5] = ag.z; in[6] = ag.w;

    float h1[40], h2[40], o[3];
    dense<7, 40, true >(w1, b1, in, h1);
    dense<40, 40, true>(w2, b2, h1, h2);
    dense<40, 3, false>(w3, b3, h2, o);

    xth[n] = make_uint2(pk2(o[0], o[1]), pk2(o[2], 0.f));
}

extern "C" void kernel_launch(void* const* d_in, const int* in_sizes, int n_in,
                              void* d_out, int out_size, void* d_ws, size_t ws_size,
                              hipStream_t stream) {
    const float* x  = (const float*)d_in[0];
    const int*   ei = (const int*)d_in[1];   // int64 delivered as int32
    const float* ea = (const float*)d_in[2];

    const float* r1_w1 = (const float*)d_in[3];
    const float* r1_b1 = (const float*)d_in[4];
    const float* r1_w2 = (const float*)d_in[5];
    const float* r1_b2 = (const float*)d_in[6];
    const float* r1_w3 = (const float*)d_in[7];
    const float* r1_b3 = (const float*)d_in[8];

    const float* o_w1 = (const float*)d_in[9];
    const float* o_b1 = (const float*)d_in[10];
    const float* o_w2 = (const float*)d_in[11];
    const float* o_b2 = (const float*)d_in[12];
    const float* o_w3 = (const float*)d_in[13];
    const float* o_b3 = (const float*)d_in[14];

    const float* r2_w1 = (const float*)d_in[15];
    const float* r2_b1 = (const float*)d_in[16];
    const float* r2_w2 = (const float*)d_in[17];
    const float* r2_b2 = (const float*)d_in[18];
    const float* r2_w3 = (const float*)d_in[19];
    const float* r2_b3 = (const float*)d_in[20];

    const int n_nodes = in_sizes[0] / 3;
    const int n_edges = in_sizes[2] / 4;
    const int B = (n_nodes + BS - 1) / BS;        // 25 buckets
    const int ntiles = (n_edges + TS - 1) / TS;   // split tiles

    // ws layout:
    //  nodef uint2[N] | emsg uint2[E] | bd u32[E] | bm uint2[E] |
    //  totals u32[NBMAX] | bases u32[NBMAX] | tilecnt u32[ntiles*NBMAX] |
    //  wtab1 uint4[NFRAG*64] | wtab2 uint4[NFRAG*64] | scratch uint2[B*S*BS]
    uint2*    nodef   = (uint2*)d_ws;
    uint2*    emsg    = nodef + n_nodes;
    unsigned* bd      = (unsigned*)(emsg + n_edges);
    uint2*    bm      = (uint2*)(bd + n_edges);
    unsigned* totals  = (unsigned*)(bm + n_edges);
    unsigned* bases   = totals + NBMAX;
    unsigned* tilecnt = bases + NBMAX;
    uint4*    wtab1   = (uint4*)(tilecnt + (size_t)ntiles * NBMAX);
    uint4*    wtab2   = wtab1 + NFRAG * 64;
    uint2*    scratch = (uint2*)(wtab2 + NFRAG * 64);

    const size_t fixed_bytes = (char*)scratch - (char*)d_ws;
    int S = 16;                                   // slices per bucket
    while (S > 4 && ws_size < fixed_bytes + (size_t)B * S * BS * sizeof(uint2))
        S >>= 1;

    const int eb = 1024;
    const int nb = (n_nodes + 255) / 256;

    wprep_kernel<<<2, 64, 0, stream>>>(r1_w1, r1_b1, r1_w2, r1_b2, r1_w3, r1_b3,
                                       r2_w1, r2_b1, r2_w2, r2_b2, r2_w3, r2_b3,
                                       wtab1, wtab2);

    nodef_kernel<<<nb, 256, 0, stream>>>(x, nodef, n_nodes);

    edge_kernel<true><<<eb, 256, 0, stream>>>(nodef, ei, (const void*)ea,
        wtab1, emsg, nullptr, n_edges);

    count_kernel<<<ntiles, TS, 0, stream>>>(ei + n_edges, tilecnt, n_edges);

    scan_kernel<<<B, 1024, 0, stream>>>(tilecnt, totals, ntiles);

    base_kernel<<<1, 64, 0, stream>>>(totals, bases, B);

    split_kernel<<<ntiles, TS, 0, stream>>>(ei + n_edges, emsg, tilecnt, bases,
                                            bd, bm, n_edges, B);

    accum_kernel<<<B * S, 1024, 0, stream>>>(bd, bm, totals, bases, scratch, S);

    node_kernel<<<nb, 256, 0, stream>>>(x, scratch,
        o_w1, o_b1, o_w2, o_b2, o_w3, o_b3, nodef, n_nodes, S);

    edge_kernel<false><<<eb, 256, 0, stream>>>(nodef, ei, (const void*)emsg,
        wtab2, nullptr, (float*)d_out, n_edges);
}

// Round 18
// 168.609 us; speedup vs baseline: 3.7165x; 1.0008x over previous
//
#include <hip/hip_runtime.h>
#include <math.h>

// Interaction Network — LDS-free MFMA edge kernels (ILP x2, wtab prologue,
// permlane32_swap transitions) + atomic-free multisplit aggregation,
// ds_pk_add_f16 bins (BS=2048), reduce fused into node kernel.
// Layer-1 K layout: k0-2 xd | 3 pad | 4-6 xs | 7 pad | 8-11 ea/msg | 12 bias | 13-15 pad
// C layout (HW-verified): col=lane&31, row=(reg&3)+8*(reg>>2)+4*(lane>>5).
// V_PERMLANE32_SWAP_B32 semantics (HW-verified r17): ret.x={lo:own A, hi:partner B},
//  ret.y={lo:partner A, hi:own B}.

typedef __fp16 hf8 __attribute__((ext_vector_type(8)));
typedef _Float16 f16x2 __attribute__((ext_vector_type(2)));
typedef float f32x16 __attribute__((ext_vector_type(16)));
typedef unsigned u32x2 __attribute__((ext_vector_type(2)));
typedef unsigned u32x4 __attribute__((ext_vector_type(4)));

#define NEPC  64    // edges per wave-chunk (two MFMA column tiles X/Y)
#define BSH   11
#define BS    (1 << BSH)  // 2048 nodes per aggregation bin (16KB f16x4 LDS)
#define NBMAX 64    // max buckets (N=100K -> 49)
#define TS    1024  // split tile size
#define NFRAG 11    // weight fragments per edge MLP

__device__ __forceinline__ f32x16 mfma16(hf8 a, hf8 b, f32x16 c) {
    return __builtin_amdgcn_mfma_f32_32x32x16_f16(a, b, c, 0, 0, 0);
}
__device__ __forceinline__ unsigned pk2(float a, float b) {
    return __builtin_bit_cast(unsigned, __builtin_amdgcn_cvt_pkrtz(a, b));
}
__device__ __forceinline__ unsigned pk2_relu(float a, float b) {
    return __builtin_bit_cast(unsigned,
        __builtin_amdgcn_cvt_pkrtz(fmaxf(a, 0.f), fmaxf(b, 0.f)));
}
__device__ __forceinline__ u32x2 pl32swap(unsigned a, unsigned b) {
    return __builtin_amdgcn_permlane32_swap(a, b, false, false);
}
__device__ __forceinline__ hf8 frag_from(unsigned a, unsigned b, unsigned c, unsigned d) {
    u32x4 v = {a, b, c, d};
    return __builtin_bit_cast(hf8, v);
}

__device__ __forceinline__ void build_frags(const f32x16& t0, const f32x16& t1,
                                            int hi, hf8& F0, hf8& F1, hf8& F2) {
    const unsigned w0 = pk2_relu(t0[0],  t0[1]);
    const unsigned w1 = pk2_relu(t0[2],  t0[3]);
    const unsigned w2 = pk2_relu(t0[4],  t0[5]);
    const unsigned w3 = pk2_relu(t0[6],  t0[7]);
    const unsigned w4 = pk2_relu(t0[8],  t0[9]);
    const unsigned w5 = pk2_relu(t0[10], t0[11]);
    const unsigned w6 = pk2_relu(t0[12], t0[13]);
    const unsigned w7 = pk2_relu(t0[14], t0[15]);
    const unsigned w8 = pk2_relu(t1[0],  t1[1]);
    const unsigned w9 = pk2_relu(t1[2],  t1[3]);
    const u32x2 r0 = pl32swap(w0, w2);
    const u32x2 r1 = pl32swap(w1, w3);
    const u32x2 r2 = pl32swap(w4, w6);
    const u32x2 r3 = pl32swap(w5, w7);
    const u32x2 r4 = pl32swap(w8, 0u);
    const u32x2 r5 = pl32swap(w9, 0u);
    F0 = frag_from(r0.x, r1.x, r0.y, r1.y);
    F1 = frag_from(r2.x, r3.x, r2.y, r3.y);
    F2 = frag_from(hi ? 0x00003c00u : w8, hi ? 0u : w9, r4.y, r5.y);
}

// hidden-layer A fragment (IN=40 + bias at k=40), runtime OUT
__device__ hf8 load_wfrag40(const float* __restrict__ w, const float* __restrict__ b,
                            int OUT, int mt, int ks, int lane) {
    const int r = mt * 32 + (lane & 31);
    const int kbase = ks * 16 + ((lane >> 5) & 1) * 8;
    hf8 f;
#pragma unroll
    for (int j = 0; j < 8; ++j) {
        const int k = kbase + j;
        float v = 0.f;
        if (r < OUT) {
            if (k < 40) v = w[r * 40 + k];
            else if (k == 40) v = b[r];
        }
        f[j] = (__fp16)v;
    }
    return f;
}

// layer-1 A fragment, padded K map (IN fixed at 10)
__device__ hf8 load_wfrag_l1(const float* __restrict__ w, const float* __restrict__ b,
                             int mt, int lane) {
    const int r = mt * 32 + (lane & 31);
    const int kbase = ((lane >> 5) & 1) * 8;
    hf8 f;
#pragma unroll
    for (int j = 0; j < 8; ++j) {
        const int k = kbase + j;
        float v = 0.f;
        if (r < 40) {
            int src = -1;
            if (k < 3) src = k;                       // xd
            else if (k >= 4 && k < 7) src = k - 1;    // xs
            else if (k >= 8 && k < 12) src = k - 2;   // ea/msg
            if (src >= 0) v = w[r * 10 + src];
            else if (k == 12) v = b[r];
        }
        f[j] = (__fp16)v;
    }
    return f;
}

// ---- weight fragment table prep (both MLPs in one launch; block 0=R1, 1=R2) ----
__global__ __launch_bounds__(64) void wprep_kernel(
    const float* __restrict__ a_w1, const float* __restrict__ a_b1,
    const float* __restrict__ a_w2, const float* __restrict__ a_b2,
    const float* __restrict__ a_w3, const float* __restrict__ a_b3,
    const float* __restrict__ b_w1, const float* __restrict__ b_b1,
    const float* __restrict__ b_w2, const float* __restrict__ b_b2,
    const float* __restrict__ b_w3, const float* __restrict__ b_b3,
    uint4* __restrict__ tab1, uint4* __restrict__ tab2)
{
    const int lane = threadIdx.x;
    const bool second = blockIdx.x == 1;
    const float* w1 = second ? b_w1 : a_w1; const float* b1 = second ? b_b1 : a_b1;
    const float* w2 = second ? b_w2 : a_w2; const float* b2 = second ? b_b2 : a_b2;
    const float* w3 = second ? b_w3 : a_w3; const float* b3 = second ? b_b3 : a_b3;
    uint4* tab = second ? tab2 : tab1;
    const int out3 = second ? 1 : 4;
#pragma unroll
    for (int t = 0; t < 2; ++t)
        tab[t * 64 + lane] = __builtin_bit_cast(uint4, load_wfrag_l1(w1, b1, t, lane));
#pragma unroll
    for (int t = 0; t < 2; ++t)
#pragma unroll
        for (int s = 0; s < 3; ++s)
            tab[(2 + t * 3 + s) * 64 + lane] =
                __builtin_bit_cast(uint4, load_wfrag40(w2, b2, 40, t, s, lane));
#pragma unroll
    for (int s = 0; s < 3; ++s)
        tab[(8 + s) * 64 + lane] =
            __builtin_bit_cast(uint4, load_wfrag40(w3, b3, out3, 0, s, lane));
}

template<bool IS_MSG>
__global__ __launch_bounds__(256, 3) void edge_kernel(
    const uint2* __restrict__ nodef,
    const int*   __restrict__ ei,
    const void*  __restrict__ eattr,
    const uint4* __restrict__ wtab,   // precomputed fragments
    uint2* __restrict__ emsg_out,
    float* __restrict__ out,
    int n_edges)
{
    const int lane = threadIdx.x & 63;
    const int ecol = lane & 31;
    const int hi = lane >> 5;

    // prologue: 11 coalesced 16B fragment loads
    hf8 wa1[2], wa2[2][3], wa3[3];
    wa1[0] = __builtin_bit_cast(hf8, wtab[0 * 64 + lane]);
    wa1[1] = __builtin_bit_cast(hf8, wtab[1 * 64 + lane]);
#pragma unroll
    for (int t = 0; t < 2; ++t)
#pragma unroll
        for (int s = 0; s < 3; ++s)
            wa2[t][s] = __builtin_bit_cast(hf8, wtab[(2 + t * 3 + s) * 64 + lane]);
#pragma unroll
    for (int s = 0; s < 3; ++s)
        wa3[s] = __builtin_bit_cast(hf8, wtab[(8 + s) * 64 + lane]);

    const int gwave = (int)((blockIdx.x * blockDim.x + threadIdx.x) >> 6);
    const int nwave = (int)((gridDim.x * blockDim.x) >> 6);
    const int nchunk = (n_edges + NEPC - 1) / NEPC;
    const int last = n_edges - 1;

    int c = gwave;
    if (c >= nchunk) return;
    auto eclampX = [&](int cc) { int e = cc * NEPC + ecol;      return e < last ? e : last; };
    auto eclampY = [&](int cc) { int e = cc * NEPC + 32 + ecol; return e < last ? e : last; };

    uint2 fAX, fBX, fAY, fBY;
    int sNX = 0, dNX = 0, sNY = 0, dNY = 0;
    {
        const int eX = eclampX(c), eY = eclampY(c);
        if (hi == 0) {
            const int sX = ei[eX], dX = ei[n_edges + eX];
            const int sY = ei[eY], dY = ei[n_edges + eY];
            fAX = nodef[dX]; fBX = nodef[sX];
            fAY = nodef[dY]; fBY = nodef[sY];
            const int e2X = eclampX(c + nwave), e2Y = eclampY(c + nwave);
            sNX = ei[e2X]; dNX = ei[n_edges + e2X];
            sNY = ei[e2Y]; dNY = ei[n_edges + e2Y];
        } else {
            if (IS_MSG) {
                const float4 evX = ((const float4*)eattr)[eX];
                fAX = make_uint2(pk2(evX.x, evX.y), pk2(evX.z, evX.w));
                const float4 evY = ((const float4*)eattr)[eY];
                fAY = make_uint2(pk2(evY.x, evY.y), pk2(evY.z, evY.w));
            } else {
                fAX = ((const uint2*)eattr)[eX];
                fAY = ((const uint2*)eattr)[eY];
            }
            fBX = make_uint2(0x00003c00u, 0u);   // bias word {1.0h, 0h}
            fBY = fBX;
        }
    }

    for (; c < nchunk; ) {
        const int cn = c + nwave;

        const hf8 bfX = frag_from(fAX.x, fAX.y, fBX.x, fBX.y);
        const hf8 bfY = frag_from(fAY.x, fAY.y, fBY.x, fBY.y);

        uint2 nfAX = fAX, nfBX = fBX, nfAY = fAY, nfBY = fBY;
        int sPX = sNX, dPX = dNX, sPY = sNY, dPY = dNY;
        {
            if (hi == 0) {
                nfAX = nodef[dNX]; nfBX = nodef[sNX];
                nfAY = nodef[dNY]; nfBY = nodef[sNY];
                const int e3X = eclampX(cn + nwave), e3Y = eclampY(cn + nwave);
                sPX = ei[e3X]; dPX = ei[n_edges + e3X];
                sPY = ei[e3Y]; dPY = ei[n_edges + e3Y];
            } else {
                const int e2X = eclampX(cn), e2Y = eclampY(cn);
                if (IS_MSG) {
                    const float4 evX = ((const float4*)eattr)[e2X];
                    nfAX = make_uint2(pk2(evX.x, evX.y), pk2(evX.z, evX.w));
                    const float4 evY = ((const float4*)eattr)[e2Y];
                    nfAY = make_uint2(pk2(evY.x, evY.y), pk2(evY.z, evY.w));
                } else {
                    nfAX = ((const uint2*)eattr)[e2X];
                    nfAY = ((const uint2*)eattr)[e2Y];
                }
            }
        }

        f32x16 a0X = {}, a1X = {}, a0Y = {}, a1Y = {};
        a0X = mfma16(wa1[0], bfX, a0X);
        a0Y = mfma16(wa1[0], bfY, a0Y);
        a1X = mfma16(wa1[1], bfX, a1X);
        a1Y = mfma16(wa1[1], bfY, a1Y);

        hf8 f0X, f1X, f2X, f0Y, f1Y, f2Y;
        build_frags(a0X, a1X, hi, f0X, f1X, f2X);
        build_frags(a0Y, a1Y, hi, f0Y, f1Y, f2Y);

        f32x16 c0X = {}, c1X = {}, c0Y = {}, c1Y = {};
        c0X = mfma16(wa2[0][0], f0X, c0X); c0Y = mfma16(wa2[0][0], f0Y, c0Y);
        c1X = mfma16(wa2[1][0], f0X, c1X); c1Y = mfma16(wa2[1][0], f0Y, c1Y);
        c0X = mfma16(wa2[0][1], f1X, c0X); c0Y = mfma16(wa2[0][1], f1Y, c0Y);
        c1X = mfma16(wa2[1][1], f1X, c1X); c1Y = mfma16(wa2[1][1], f1Y, c1Y);
        c0X = mfma16(wa2[0][2], f2X, c0X); c0Y = mfma16(wa2[0][2], f2Y, c0Y);
        c1X = mfma16(wa2[1][2], f2X, c1X); c1Y = mfma16(wa2[1][2], f2Y, c1Y);

        hf8 g0X, g1X, g2X, g0Y, g1Y, g2Y;
        build_frags(c0X, c1X, hi, g0X, g1X, g2X);
        build_frags(c0Y, c1Y, hi, g0Y, g1Y, g2Y);

        f32x16 z0X = {}, z0Y = {};
        z0X = mfma16(wa3[0], g0X, z0X); z0Y = mfma16(wa3[0], g0Y, z0Y);
        z0X = mfma16(wa3[1], g1X, z0X); z0Y = mfma16(wa3[1], g1Y, z0Y);
        z0X = mfma16(wa3[2], g2X, z0X); z0Y = mfma16(wa3[2], g2Y, z0Y);

        if (hi == 0) {
            const int eX = c * NEPC + ecol;
            const int eY = eX + 32;
            if (eX < n_edges) {
                if (IS_MSG)
                    emsg_out[eX] = make_uint2(pk2(z0X[0], z0X[1]), pk2(z0X[2], z0X[3]));
                else
                    out[eX] = 1.f / (1.f + expf(-z0X[0]));
            }
            if (eY < n_edges) {
                if (IS_MSG)
                    emsg_out[eY] = make_uint2(pk2(z0Y[0], z0Y[1]), pk2(z0Y[2], z0Y[3]));
                else
                    out[eY] = 1.f / (1.f + expf(-z0Y[0]));
            }
        }

        fAX = nfAX; fBX = nfBX; fAY = nfAY; fBY = nfBY;
        sNX = sPX; dNX = dPX; sNY = sPY; dNY = dPY;
        c = cn;
    }
}

// ---- node feature packing ----
__global__ __launch_bounds__(256) void nodef_kernel(
    const float* __restrict__ x, uint2* __restrict__ nodef, int n_nodes)
{
    int n = blockIdx.x * blockDim.x + threadIdx.x;
    if (n >= n_nodes) return;
    nodef[n] = make_uint2(pk2(x[n * 3 + 0], x[n * 3 + 1]), pk2(x[n * 3 + 2], 0.f));
}

// ---- A: per-(tile,bucket) counts (LDS atomics only) ----
__global__ __launch_bounds__(TS) void count_kernel(
    const int* __restrict__ dstp, unsigned* __restrict__ tilecnt, int n_edges)
{
    __shared__ unsigned lc[NBMAX];
    const int tid = threadIdx.x;
    if (tid < NBMAX) lc[tid] = 0u;
    __syncthreads();
    const int e = blockIdx.x * TS + tid;
    if (e < n_edges) atomicAdd(&lc[((unsigned)dstp[e]) >> BSH], 1u);
    __syncthreads();
    if (tid < NBMAX) tilecnt[(size_t)blockIdx.x * NBMAX + tid] = lc[tid];
}

// ---- B: per-bucket exclusive prefix over tiles (in place) + totals ----
__global__ __launch_bounds__(1024) void scan_kernel(
    unsigned* __restrict__ tilecnt, unsigned* __restrict__ totals, int ntiles)
{
    __shared__ unsigned buf[1024];
    const int b = blockIdx.x;
    const int tid = threadIdx.x;
    unsigned carry = 0;
    for (int base = 0; base < ntiles; base += 1024) {
        const int i = base + tid;
        const unsigned v = (i < ntiles) ? tilecnt[(size_t)i * NBMAX + b] : 0u;
        buf[tid] = v;
        __syncthreads();
        for (int off = 1; off < 1024; off <<= 1) {
            const unsigned t = (tid >= off) ? buf[tid - off] : 0u;
            __syncthreads();
            buf[tid] += t;
            __syncthreads();
        }
        if (i < ntiles) tilecnt[(size_t)i * NBMAX + b] = (buf[tid] - v) + carry;
        carry += buf[1023];
        __syncthreads();
    }
    if (tid == 0) totals[b] = carry;
}

// ---- C: exclusive scan of bucket totals ----
__global__ __launch_bounds__(64) void base_kernel(
    const unsigned* __restrict__ totals, unsigned* __restrict__ bases, int nbins)
{
    if (threadIdx.x == 0) {
        unsigned run = 0;
        for (int i = 0; i < nbins; ++i) { bases[i] = run; run += totals[i]; }
    }
}

// ---- D: multisplit scatter (SoA output), static offsets ----
__global__ __launch_bounds__(TS) void split_kernel(
    const int* __restrict__ dstp,
    const uint2* __restrict__ emsg,
    const unsigned* __restrict__ tilecnt,   // exclusive per-tile offsets
    const unsigned* __restrict__ bases,
    unsigned* __restrict__ bd,              // dst per record, bucket-contiguous
    uint2* __restrict__ bm,                 // msg per record
    int n_edges, int nbins)
{
    __shared__ unsigned lcnt[NBMAX], loff[NBMAX], gbase[NBMAX];
    __shared__ unsigned stage[TS * 3];      // 12KB
    const int tid = threadIdx.x;
    const int e = blockIdx.x * TS + tid;
    const bool valid = e < n_edges;

    if (tid < NBMAX) lcnt[tid] = 0u;
    __syncthreads();

    unsigned d = 0, b = 0, slot = 0; uint2 m = make_uint2(0u, 0u);
    if (valid) {
        d = (unsigned)dstp[e];
        m = emsg[e];
        b = d >> BSH;
        slot = atomicAdd(&lcnt[b], 1u);
    }
    __syncthreads();

    if (tid < NBMAX && tid < (unsigned)nbins) {
        gbase[tid] = bases[tid] + tilecnt[(size_t)blockIdx.x * NBMAX + tid];
    }
    if (tid == 0) {
        unsigned run = 0;
        for (int i = 0; i < nbins; ++i) { loff[i] = run; run += lcnt[i]; }
    }
    __syncthreads();

    if (valid) {
        const unsigned p = (loff[b] + slot) * 3;
        stage[p] = d; stage[p + 1] = m.x; stage[p + 2] = m.y;
    }
    __syncthreads();

    const int total = min(TS, n_edges - blockIdx.x * TS);
    if (tid < total) {
        const unsigned dd = stage[tid * 3];
        const unsigned bb = dd >> BSH;
        const unsigned gpos = gbase[bb] + ((unsigned)tid - loff[bb]);
        bd[gpos] = dd;
        bm[gpos] = make_uint2(stage[tid * 3 + 1], stage[tid * 3 + 2]);
    }
}

// ---- E: dense per-(bucket,slice) scan -> f16x4 LDS bins via ds_pk_add_f16,
//      x4 unrolled (4 dense loads in flight per thread-iteration) ----
typedef _Float16 hf2 __attribute__((ext_vector_type(2)));
__device__ __forceinline__ void pk_accum(unsigned* __restrict__ bin,
                                         unsigned d, uint2 m) {
    const unsigned laddr =
        (unsigned)(reinterpret_cast<uintptr_t>(&bin[(d & (BS - 1)) * 2]));
    asm volatile("ds_pk_add_f16 %0, %1" :: "v"(laddr), "v"(m.x) : "memory");
    asm volatile("ds_pk_add_f16 %0, %1 offset:4" :: "v"(laddr), "v"(m.y) : "memory");
}

__global__ __launch_bounds__(1024) void accum_kernel(
    const unsigned* __restrict__ bd,
    const uint2* __restrict__ bm,
    const unsigned* __restrict__ totals,
    const unsigned* __restrict__ bases,
    uint2* __restrict__ scratch,      // [B*S][BS] f16x4 partials
    int S)
{
    __shared__ unsigned bin[BS * 2];  // 16 KB, f16x4 per node
    const int bid = blockIdx.x / S, s = blockIdx.x % S;
    const int tid = threadIdx.x;

#pragma unroll
    for (int i = 0; i < (BS * 2) / 1024; ++i)
        bin[tid + i * 1024] = 0u;
    __syncthreads();

    const unsigned start = bases[bid], len = totals[bid];
    const unsigned r0 = start + (unsigned)((unsigned long long)len * s / S);
    const unsigned r1 = start + (unsigned)((unsigned long long)len * (s + 1) / S);

    unsigned r = r0 + tid;
    for (; r + 3072 < r1; r += 4096) {
        const unsigned d0 = bd[r], d1 = bd[r + 1024], d2 = bd[r + 2048], d3 = bd[r + 3072];
        const uint2 m0 = bm[r], m1 = bm[r + 1024], m2 = bm[r + 2048], m3 = bm[r + 3072];
        pk_accum(bin, d0, m0);
        pk_accum(bin, d1, m1);
        pk_accum(bin, d2, m2);
        pk_accum(bin, d3, m3);
    }
    for (; r < r1; r += 1024)
        pk_accum(bin, bd[r], bm[r]);
    __syncthreads();

    uint2* dst = scratch + (size_t)(bid * S + s) * BS;
    const uint2* srcb = (const uint2*)bin;
#pragma unroll
    for (int i = 0; i < BS / 1024; ++i)
        dst[tid + i * 1024] = srcb[tid + i * 1024];
}

template<int IN, int OUT, bool RELU>
__device__ __forceinline__ void dense(const float* __restrict__ w,
                                      const float* __restrict__ b,
                                      const float* in, float* out) {
#pragma unroll
    for (int j = 0; j < OUT; ++j) {
        float acc = b[j];
#pragma unroll
        for (int k = 0; k < IN; ++k) acc = fmaf(w[j * IN + k], in[k], acc);
        out[j] = RELU ? fmaxf(acc, 0.f) : acc;
    }
}

// ---- node update, with slice-reduction fused (reads S f16x4 partials) ----
__global__ __launch_bounds__(256) void node_kernel(
    const float* __restrict__ x,
    const uint2* __restrict__ scratch,
    const float* __restrict__ w1, const float* __restrict__ b1,
    const float* __restrict__ w2, const float* __restrict__ b2,
    const float* __restrict__ w3, const float* __restrict__ b3,
    uint2* __restrict__ xth,
    int n_nodes, int S)
{
    int n = blockIdx.x * blockDim.x + threadIdx.x;
    if (n >= n_nodes) return;

    const int b = n >> BSH, nl = n & (BS - 1);
    float4 ag = make_float4(0.f, 0.f, 0.f, 0.f);
    for (int w = 0; w < S; ++w) {
        const uint2 v = scratch[(size_t)(b * S + w) * BS + nl];
        const hf2 lo = __builtin_bit_cast(hf2, v.x);
        const hf2 hi = __builtin_bit_cast(hf2, v.y);
        ag.x += (float)lo.x; ag.y += (float)lo.y;
        ag.z += (float)hi.x; ag.w += (float)hi.y;
    }

    float in[7];
    in[0] = x[n * 3 + 0]; in[1] = x[n * 3 + 1]; in[2] = x[n * 3 + 2];
    in[3] = ag.x; in[4] = ag.y; in[5] = ag.z; in[6] = ag.w;

    float h1[40], h2[40], o[3];
    dense<7, 40, true >(w1, b1, in, h1);
    dense<40, 40, true>(w2, b2, h1, h2);
    dense<40, 3, false>(w3, b3, h2, o);

    xth[n] = make_uint2(pk2(o[0], o[1]), pk2(o[2], 0.f));
}

extern "C" void kernel_launch(void* const* d_in, const int* in_sizes, int n_in,
                              void* d_out, int out_size, void* d_ws, size_t ws_size,
                              hipStream_t stream) {
    const float* x  = (const float*)d_in[0];
    const int*   ei = (const int*)d_in[1];   // int64 delivered as int32
    const float* ea = (const float*)d_in[2];

    const float* r1_w1 = (const float*)d_in[3];
    const float* r1_b1 = (const float*)d_in[4];
    const float* r1_w2 = (const float*)d_in[5];
    const float* r1_b2 = (const float*)d_in[6];
    const float* r1_w3 = (const float*)d_in[7];
    const float* r1_b3 = (const float*)d_in[8];

    const float* o_w1 = (const float*)d_in[9];
    const float* o_b1 = (const float*)d_in[10];
    const float* o_w2 = (const float*)d_in[11];
    const float* o_b2 = (const float*)d_in[12];
    const float* o_w3 = (const float*)d_in[13];
    const float* o_b3 = (const float*)d_in[14];

    const float* r2_w1 = (const float*)d_in[15];
    const float* r2_b1 = (const float*)d_in[16];
    const float* r2_w2 = (const float*)d_in[17];
    const float* r2_b2 = (const float*)d_in[18];
    const float* r2_w3 = (const float*)d_in[19];
    const float* r2_b3 = (const float*)d_in[20];

    const int n_nodes = in_sizes[0] / 3;
    const int n_edges = in_sizes[2] / 4;
    const int B = (n_nodes + BS - 1) / BS;        // 49 buckets
    const int ntiles = (n_edges + TS - 1) / TS;   // split tiles

    // ws layout:
    //  nodef uint2[N] | emsg uint2[E] | bd u32[E] | bm uint2[E] |
    //  totals u32[NBMAX] | bases u32[NBMAX] | tilecnt u32[ntiles*NBMAX] |
    //  wtab1 uint4[NFRAG*64] | wtab2 uint4[NFRAG*64] | scratch uint2[B*S*BS]
    uint2*    nodef   = (uint2*)d_ws;
    uint2*    emsg    = nodef + n_nodes;
    unsigned* bd      = (unsigned*)(emsg + n_edges);
    uint2*    bm      = (uint2*)(bd + n_edges);
    unsigned* totals  = (unsigned*)(bm + n_edges);
    unsigned* bases   = totals + NBMAX;
    unsigned* tilecnt = bases + NBMAX;
    uint4*    wtab1   = (uint4*)(tilecnt + (size_t)ntiles * NBMAX);
    uint4*    wtab2   = wtab1 + NFRAG * 64;
    uint2*    scratch = (uint2*)(wtab2 + NFRAG * 64);

    const size_t fixed_bytes = (char*)scratch - (char*)d_ws;
    int S = 8;                                    // slices per bucket
    while (S > 2 && ws_size < fixed_bytes + (size_t)B * S * BS * sizeof(uint2))
        S >>= 1;

    const int eb = 1024;
    const int nb = (n_nodes + 255) / 256;

    wprep_kernel<<<2, 64, 0, stream>>>(r1_w1, r1_b1, r1_w2, r1_b2, r1_w3, r1_b3,
                                       r2_w1, r2_b1, r2_w2, r2_b2, r2_w3, r2_b3,
                                       wtab1, wtab2);

    nodef_kernel<<<nb, 256, 0, stream>>>(x, nodef, n_nodes);

    edge_kernel<true><<<eb, 256, 0, stream>>>(nodef, ei, (const void*)ea,
        wtab1, emsg, nullptr, n_edges);

    count_kernel<<<ntiles, TS, 0, stream>>>(ei + n_edges, tilecnt, n_edges);

    scan_kernel<<<B, 1024, 0, stream>>>(tilecnt, totals, ntiles);

    base_kernel<<<1, 64, 0, stream>>>(totals, bases, B);

    split_kernel<<<ntiles, TS, 0, stream>>>(ei + n_edges, emsg, tilecnt, bases,
                                            bd, bm, n_edges, B);

    accum_kernel<<<B * S, 1024, 0, stream>>>(bd, bm, totals, bases, scratch, S);

    node_kernel<<<nb, 256, 0, stream>>>(x, scratch,
        o_w1, o_b1, o_w2, o_b2, o_w3, o_b3, nodef, n_nodes, S);

    edge_kernel<false><<<eb, 256, 0, stream>>>(nodef, ei, (const void*)emsg,
        wtab2, nullptr, (float*)d_out, n_edges);
}